// Round 11
// baseline (333.037 us; speedup 1.0000x reference)
//
#include <hip/hip_runtime.h>
#include <hip/hip_bf16.h>

// ---------------------------------------------------------------------------
// SJCSNN: conv1+bn1 -> IF -> pool -> conv2+bn2 -> IF -> pool -> fc1 -> LIF ->
//         fc2 -> LIF -> fc3 -> LIF -> mean over T.  T=8, B=32.
// Spikes are binary => exact in bf16 => MFMA with hi/lo-split fp32 weights
// gives fp32-identical threshold decisions (absmax == 0.0 across rounds).
// conv2 (FROZEN, ~101us): R5 1-phase gload_lds + R11 grid swap (b fastest).
// R12 (kept): fc1_reduce 32-wide load ILP; prep+conv1 merged; tail unroll 8.
// R13 (kept, best 328.1): fc1_gemm N-retile 64 -> 576 blocks (full machine).
// R14 (REVERTED): reduce fused into 32-block tail starved part read (+6.6us).
// R15 (REVERTED): tail fc2/fc3 split = null vs R13 (+1 launch, no gain);
//   calibration: extra launch cost ~0.4us => non-conv2 time is in-kernel.
// R16: fc1_gemm B-prefetch depth 1 -> 2 (qa/qb rotation, static regs).
//   Cover math: 1 substage compute ~960cy/SIMD vs ~900cy cold-HBM latency,
//   borderline at 2-3 blocks/CU contention. Same loads/cvt/MFMA order =>
//   bitwise identical.
// ---------------------------------------------------------------------------

typedef float  f32x4  __attribute__((ext_vector_type(4)));
typedef __bf16 bf16x8 __attribute__((ext_vector_type(8)));

#define T_STEPS 8

// ---- workspace layout (bytes) ----
static const size_t OFF_P1    = 0;                  // p1pad 44,302,336 (dead after conv2)
static const size_t OFF_PART  = 0;                  // fc1 partials 37,748,736 (reuse)
static const size_t OFF_WT    = 44302336;           // 1,179,648 (hi+lo conv2 weights)
static const size_t OFF_P2    = 45481984;           // 9,437,184
static const size_t OFF_W2T   = 54919168;           //   589,824
static const size_t OFF_L1S   = 55508992;           // 1,179,648  (end 56,688,640)

__device__ __forceinline__ unsigned short bf16_rne(float f) {
  unsigned u = __builtin_bit_cast(unsigned, f);
  u += 0x7FFFu + ((u >> 16) & 1u);
  return (unsigned short)(u >> 16);
}
__device__ __forceinline__ float bf16_to_f(unsigned short h) {
  unsigned u = ((unsigned)h) << 16;
  return __builtin_bit_cast(float, u);
}

// packed split: two fp32 -> packed hi-bf16 pair + packed lo-bf16 pair.
__device__ __forceinline__ void split_pair(float f0, float f1, unsigned& hi, unsigned& lo) {
  __hip_bfloat162 h2 = __float22bfloat162_rn(make_float2(f0, f1));
  unsigned uh; __builtin_memcpy(&uh, &h2, 4);
  float g0 = __builtin_bit_cast(float, uh << 16);
  float g1 = __builtin_bit_cast(float, uh & 0xFFFF0000u);
  __hip_bfloat162 l2 = __float22bfloat162_rn(make_float2(f0 - g0, f1 - g1));
  unsigned ul; __builtin_memcpy(&ul, &l2, 4);
  hi = uh;
  lo = ul;
}

__device__ __forceinline__ void lds_load16(const void* g, void* l) {
  auto* gp = reinterpret_cast<const __attribute__((address_space(1))) unsigned int*>(
      reinterpret_cast<uintptr_t>(g));
  auto* lp = reinterpret_cast<__attribute__((address_space(3))) unsigned int*>(
      reinterpret_cast<uintptr_t>(l));
  __builtin_amdgcn_global_load_lds(gp, lp, 16, 0, 0);
}

// ---------------------------------------------------------------------------
// merged prep + conv1.  Blocks [0,2752): prep (conv2_w hi/lo split, fc2_w
// transpose, p1pad border zero).  Blocks [2752,11968): conv1+bn1 -> IF(T) ->
// pool, 2 spatial positions per 256-thread block.
__global__ __launch_bounds__(256) void prep_conv1(
    const float* __restrict__ conv2_w, const float* __restrict__ fc2_w,
    short* __restrict__ wt_hi, short* __restrict__ wt_lo, float* __restrict__ w2t,
    uint4* __restrict__ p1pad4,
    const float* __restrict__ x, const float* __restrict__ w1, const float* __restrict__ b1,
    const float* __restrict__ g1, const float* __restrict__ be1, const float* __restrict__ m1,
    const float* __restrict__ vv1, short* __restrict__ p1) {
  __shared__ float patch[2][16];
  const int bx = blockIdx.x;
  if (bx < 2752) {
    // ---- prep ----
    int i = bx * 256 + threadIdx.x;                  // < 704512
    if (i < 147456) {
      int tap = i >> 14;
      int oc  = (i >> 7) & 127;
      int ic  = i & 127;
      float wv = conv2_w[oc * 1152 + ic * 9 + tap];
      unsigned short h = bf16_rne(wv);
      wt_hi[i] = (short)h;
      wt_lo[i] = (short)bf16_rne(wv - bf16_to_f(h));
    } else if (i < 294912) {
      int j = i - 147456;
      int o = j & 127, k = j >> 7;
      w2t[j] = fc2_w[o * 1152 + k];
    } else {
      int k = i - 294912;                            // 256 tb x 100 border pos x 16 uint4
      int tb = k / 1600;
      int rem = k - tb * 1600;
      int pos = rem >> 4, c8 = rem & 15;
      int y, xx;
      if (pos < 26)      { y = 0;  xx = pos; }
      else if (pos < 52) { y = 25; xx = pos - 26; }
      else { int jj = pos - 52; y = 1 + (jj >> 1); xx = (jj & 1) * 25; }
      p1pad4[(tb * 676 + y * 26 + xx) * 16 + c8] = make_uint4(0u, 0u, 0u, 0u);
    }
    return;
  }
  // ---- conv1: bid in [0,9216): b = bid/288, sp-pair = bid%288 ----
  const int bid  = bx - 2752;
  const int b    = bid / 288;
  const int spp  = bid - b * 288;
  const int half = threadIdx.x >> 7;                 // 0/1: which sp of the pair
  const int sp   = spp * 2 + half;                   // 0..575
  const int c    = threadIdx.x & 127;
  const int oy = sp / 24, ox = sp % 24;
  if (c < 16) {
    int py = c >> 2, px = c & 3;
    int iy = 2 * oy - 1 + py, ix = 2 * ox - 1 + px;
    float v = 0.f;
    if (iy >= 0 && iy < 48 && ix >= 0 && ix < 48) v = x[b * 2304 + iy * 48 + ix];
    patch[half][c] = v;
  }
  __syncthreads();
  float w[9];
#pragma unroll
  for (int i = 0; i < 9; ++i) w[i] = w1[c * 9 + i];
  float scale = g1[c] * rsqrtf(vv1[c] + 1e-5f);
  float shift = (b1[c] - m1[c]) * scale + be1[c];
  float h[4];
#pragma unroll
  for (int p = 0; p < 4; ++p) {
    int py = p >> 1, px = p & 1;
    float s = 0.f;
#pragma unroll
    for (int dy = 0; dy < 3; ++dy)
#pragma unroll
      for (int dx = 0; dx < 3; ++dx) s += patch[half][(py + dy) * 4 + (px + dx)] * w[dy * 3 + dx];
    h[p] = s * scale + shift;
  }
  float va = 0.f, vb = 0.f, vc = 0.f, vd = 0.f;
  size_t base = ((size_t)b * 676 + (size_t)(1 + oy) * 26 + (1 + ox)) * 128 + c;
#pragma unroll
  for (int t = 0; t < T_STEPS; ++t) {
    va += h[0]; vb += h[1]; vc += h[2]; vd += h[3];
    bool s0 = va >= 1.f, s1 = vb >= 1.f, s2 = vc >= 1.f, s3 = vd >= 1.f;
    p1[base + (size_t)t * (32 * 676 * 128)] = (s0 | s1 | s2 | s3) ? (short)0x3F80 : (short)0;
    if (s0) va = 0.f; if (s1) vb = 0.f; if (s2) vc = 0.f; if (s3) vd = 0.f;
  }
}

// conv2 implicit-im2col MFMA GEMM, 256x128 block tile (4 waves x 128x64),
// fused bn2 + IF(T) + 2x2 maxpool epilogue. [FROZEN: R5 structure + R11 swap]
__global__ __launch_bounds__(256, 2) void conv2_gemm(
    const short* __restrict__ p1pad, const short* __restrict__ wt_hi, const short* __restrict__ wt_lo,
    const float* __restrict__ conv2_b, const float* __restrict__ bn2_g, const float* __restrict__ bn2_b,
    const float* __restrict__ bn2_m, const float* __restrict__ bn2_v, short* __restrict__ p2) {
  __shared__ __align__(16) short lds[32768];        // A:16384  Bh:8192  Bl:8192 shorts (64 KB)
  short* ldsA  = lds;
  short* ldsBh = lds + 16384;
  short* ldsBl = lds + 24576;

  const int tid = threadIdx.x;
  const int lane = tid & 63;
  const int w = tid >> 6;                           // 0..3
  const int wm = w & 1, wn = w >> 1;
  const int b  = blockIdx.x;                        // b fastest -> XCD = b%8
  const int sp = blockIdx.y;                        // 0..17 spatial tile
  const int gy = sp / 3;
  const int gx = sp - gy * 3;

  const int g = (lane & 7) ^ (lane >> 3);
  int rowofsA[8], bofs[4];
#pragma unroll
  for (int j = 0; j < 8; ++j) {
    int r = w * 64 + j * 8 + (lane >> 3);
    int t = r >> 5, iy = (r >> 3) & 3, ix = r & 7;
    rowofsA[j] = (((t * 32 + b) * 676) + (4 * gy + iy) * 26 + (8 * gx + ix)) * 128 + g * 8;
  }
#pragma unroll
  for (int j = 0; j < 4; ++j) {
    int n = w * 32 + j * 8 + (lane >> 3);
    bofs[j] = n * 128 + g * 8;
  }

  f32x4 acc[8][4];
#pragma unroll
  for (int mi = 0; mi < 8; ++mi)
#pragma unroll
    for (int ni = 0; ni < 4; ++ni) acc[mi][ni] = (f32x4){0.f, 0.f, 0.f, 0.f};

#pragma unroll 1
  for (int s = 0; s < 18; ++s) {
    const int tap = s >> 1;
    const int kk = (s & 1) << 6;
    const int tapoff = ((tap / 3) * 26 + (tap % 3)) * 128;
    __syncthreads();
#pragma unroll
    for (int j = 0; j < 8; ++j) {
      lds_load16(p1pad + rowofsA[j] + tapoff + kk, ldsA + (w * 64 + j * 8) * 64 + lane * 8);
    }
    const int wtoff = tap * 16384 + kk;
#pragma unroll
    for (int j = 0; j < 4; ++j) {
      lds_load16(wt_hi + wtoff + bofs[j], ldsBh + (w * 32 + j * 8) * 64 + lane * 8);
      lds_load16(wt_lo + wtoff + bofs[j], ldsBl + (w * 32 + j * 8) * 64 + lane * 8);
    }
    __syncthreads();
#pragma unroll
    for (int ks = 0; ks < 2; ++ks) {
      const int cch = ks * 4 + (lane >> 4);
      bf16x8 a[8], bh[4], bl[4];
#pragma unroll
      for (int i = 0; i < 8; ++i) {
        int r = wm * 128 + i * 16 + (lane & 15);
        a[i] = *(const bf16x8*)(ldsA + r * 64 + ((cch ^ (r & 7)) * 8));
      }
#pragma unroll
      for (int i = 0; i < 4; ++i) {
        int n = wn * 64 + i * 16 + (lane & 15);
        bh[i] = *(const bf16x8*)(ldsBh + n * 64 + ((cch ^ (n & 7)) * 8));
        bl[i] = *(const bf16x8*)(ldsBl + n * 64 + ((cch ^ (n & 7)) * 8));
      }
#pragma unroll
      for (int mi = 0; mi < 8; ++mi)
#pragma unroll
        for (int ni = 0; ni < 4; ++ni) {
          acc[mi][ni] = __builtin_amdgcn_mfma_f32_16x16x32_bf16(a[mi], bh[ni], acc[mi][ni], 0, 0, 0);
          acc[mi][ni] = __builtin_amdgcn_mfma_f32_16x16x32_bf16(a[mi], bl[ni], acc[mi][ni], 0, 0, 0);
        }
    }
  }

  // ---- fused epilogue: 4 quarters of 64 rows (= t-pairs, sequential in t).
  float sc[4], sh[4];
#pragma unroll
  for (int ni = 0; ni < 4; ++ni) {
    int oc = wn * 64 + ni * 16 + (lane & 15);
    sc[ni] = bn2_g[oc] * rsqrtf(bn2_v[oc] + 1e-5f);
    sh[ni] = (conv2_b[oc] - bn2_m[oc]) * sc[ni] + bn2_b[oc];
  }
  float* ybuf = (float*)lds;                        // 64 rows x stride 132 floats
  const int S = 132;
  float v[32];
#pragma unroll
  for (int q = 0; q < 32; ++q) v[q] = 0.f;
  unsigned short* p2u = (unsigned short*)p2;
  __syncthreads();
#pragma unroll
  for (int q = 0; q < 4; ++q) {                     // FULLY UNROLLED (acc idx const)
    if (wm == (q >> 1)) {
      const int mib = (q & 1) * 4;
#pragma unroll
      for (int ml = 0; ml < 4; ++ml)
#pragma unroll
        for (int ni = 0; ni < 4; ++ni)
#pragma unroll
          for (int r = 0; r < 4; ++r) {
            int lam = ml * 16 + ((lane >> 4) << 2) + r;
            int col = wn * 64 + ni * 16 + (lane & 15);
            ybuf[lam * S + col] = acc[mib + ml][ni][r] * sc[ni] + sh[ni];
          }
    }
    __syncthreads();
    if (tid < 128) {
      const int oc = tid;
#pragma unroll
      for (int tt = 0; tt < 2; ++tt) {
        int t = 2 * q + tt;
#pragma unroll
        for (int pooly = 0; pooly < 2; ++pooly) {
          unsigned short ov[4];
#pragma unroll
          for (int poolx = 0; poolx < 4; ++poolx) {
            bool any = false;
#pragma unroll
            for (int ry = 0; ry < 2; ++ry)
#pragma unroll
              for (int rx = 0; rx < 2; ++rx) {
                int iy = 2 * pooly + ry, ix = 2 * poolx + rx;
                float xx = ybuf[(tt * 32 + iy * 8 + ix) * S + oc];
                int qi = iy * 8 + ix;
                v[qi] += xx;
                bool ss = v[qi] >= 1.f;
                any |= ss;
                if (ss) v[qi] = 0.f;
              }
            ov[poolx] = any ? (unsigned short)0x3F80 : (unsigned short)0;
          }
          ushort4 o4; o4.x = ov[0]; o4.y = ov[1]; o4.z = ov[2]; o4.w = ov[3];
          *(ushort4*)(p2u + ((size_t)(t * 32 + b) * 128 + oc) * 144 + (2 * gy + pooly) * 12 + 4 * gx) = o4;
        }
      }
    }
    __syncthreads();
  }
}

// fc1: M=256, N=1152, K=18432 split 32 ways.  R13: N-tiles of 64 -> grid
// 18x32 = 576 blocks (full machine), LDS 48KB, acc[4][2].
// R16: B register prefetch deepened to 2 substages (qa = current, qb = next;
// static rotation, no dynamic reg indexing). Same loads/cvt/MFMA order =>
// bitwise-identical partials.
__global__ __launch_bounds__(512) void fc1_gemm(const short* __restrict__ p2,
                                                const float* __restrict__ fc1_w,
                                                float* __restrict__ part) {
  __shared__ __align__(16) short lds[24576];        // A:16384  Bh:4096  Bl:4096 (48 KB)
  short* ldsA = lds;
  short* ldsBh = lds + 16384;
  short* ldsBl = lds + 20480;

  const int tid = threadIdx.x;
  const int lane = tid & 63;
  const int w = tid >> 6;                           // 0..7
  const int wm = w & 3, wn = w >> 2;                // wm: 64-row quarter; wn: 32-col half
  const int nt2 = blockIdx.x;                       // 0..17 N-tile of 64 cols
  const int n0 = nt2 * 64;
  const int kb = blockIdx.y * 576;

  const int g = (lane & 7) ^ (lane >> 3);
  int aofs[4];
#pragma unroll
  for (int j = 0; j < 4; ++j) {
    int r = w * 32 + j * 8 + (lane >> 3);
    aofs[j] = r * 18432 + g * 8;
  }
  const int bn = tid >> 3;                          // 0..63 B row
  const int c0 = tid & 7;                           // chunk of 8 floats
  const float* wrow = fc1_w + (size_t)(n0 + bn) * 18432 + c0 * 8;
  const int bpos = (c0 ^ (bn & 7)) * 8;

  f32x4 acc[4][2];
#pragma unroll
  for (int mi = 0; mi < 4; ++mi)
#pragma unroll
    for (int ni = 0; ni < 2; ++ni) acc[mi][ni] = (f32x4){0.f, 0.f, 0.f, 0.f};

  // prologue: B regs for substage 0 (qa) and substage 1 (qb)
  float4 qa0, qa1, qb0, qb1;
  {
    const float4* wp = (const float4*)(wrow + kb);
    qa0 = wp[0]; qa1 = wp[1];
  }
  {
    const float4* wp = (const float4*)(wrow + kb + 64);
    qb0 = wp[0]; qb1 = wp[1];
  }

#pragma unroll 1
  for (int s = 0; s < 9; ++s) {
    const int koff = kb + s * 64;
    __syncthreads();
#pragma unroll
    for (int j = 0; j < 4; ++j) {
      lds_load16(p2 + aofs[j] + koff, ldsA + (w * 32 + j * 8) * 64 + lane * 8);
    }
    {
      unsigned h0, h1, h2, h3, l0, l1, l2, l3;
      split_pair(qa0.x, qa0.y, h0, l0);
      split_pair(qa0.z, qa0.w, h1, l1);
      split_pair(qa1.x, qa1.y, h2, l2);
      split_pair(qa1.z, qa1.w, h3, l3);
      uint4 H; H.x = h0; H.y = h1; H.z = h2; H.w = h3;
      uint4 L; L.x = l0; L.y = l1; L.z = l2; L.w = l3;
      *(uint4*)(ldsBh + bn * 64 + bpos) = H;
      *(uint4*)(ldsBl + bn * 64 + bpos) = L;
    }
    qa0 = qb0; qa1 = qb1;                           // rotate: next -> current
    if (s < 7) {                                    // prefetch substage s+2
      const float4* wp = (const float4*)(wrow + koff + 128);
      qb0 = wp[0]; qb1 = wp[1];
    }
    __builtin_amdgcn_sched_barrier(0);              // keep prefetch above the barrier
    __syncthreads();
#pragma unroll
    for (int ks = 0; ks < 2; ++ks) {
      bf16x8 a[4], bh[2], bl[2];
      const int cch = ks * 4 + (lane >> 4);
#pragma unroll
      for (int i = 0; i < 4; ++i) {
        int r = wm * 64 + i * 16 + (lane & 15);
        a[i] = *(const bf16x8*)(ldsA + r * 64 + ((cch ^ (r & 7)) * 8));
      }
#pragma unroll
      for (int i = 0; i < 2; ++i) {
        int n = wn * 32 + i * 16 + (lane & 15);
        bh[i] = *(const bf16x8*)(ldsBh + n * 64 + ((cch ^ (n & 7)) * 8));
        bl[i] = *(const bf16x8*)(ldsBl + n * 64 + ((cch ^ (n & 7)) * 8));
      }
#pragma unroll
      for (int mi = 0; mi < 4; ++mi)
#pragma unroll
        for (int ni = 0; ni < 2; ++ni) {
          acc[mi][ni] = __builtin_amdgcn_mfma_f32_16x16x32_bf16(a[mi], bh[ni], acc[mi][ni], 0, 0, 0);
          acc[mi][ni] = __builtin_amdgcn_mfma_f32_16x16x32_bf16(a[mi], bl[ni], acc[mi][ni], 0, 0, 0);
        }
    }
  }
  const int nt = nt2 >> 1;                          // 128-col tile for part layout
  const int jbase = (nt2 & 1) * 64;
  const size_t pbase = (size_t)(blockIdx.y * 9 + nt) * 32768;
#pragma unroll
  for (int ni = 0; ni < 2; ++ni) {
    int j = jbase + wn * 32 + ni * 16 + (lane & 15);
#pragma unroll
    for (int mi = 0; mi < 4; ++mi) {
#pragma unroll
      for (int r = 0; r < 4; ++r) {
        int m = wm * 64 + mi * 16 + ((lane >> 4) << 2) + r;
        part[pbase + (size_t)m * 128 + j] = acc[mi][ni][r];
      }
    }
  }
}

// split-K reduce + bias + LIF over T, writing l1 spikes.  [R12/R13 state]
__global__ __launch_bounds__(128) void fc1_reduce_lif(const float* __restrict__ part,
                                                      const float* __restrict__ fc1_b,
                                                      float* __restrict__ l1s) {
  int i = blockIdx.x * 128 + threadIdx.x;           // < 36864 : (b, n)
  int b = i / 1152, n = i - b * 1152;
  int nt = n >> 7, j = n & 127;
  float bias = fc1_b[n];
  float v = 0.f;
#pragma unroll
  for (int t = 0; t < T_STEPS; ++t) {
    int m = t * 32 + b;
    float vals[32];
#pragma unroll
    for (int ks = 0; ks < 32; ++ks)
      vals[ks] = part[(((size_t)ks * 9 + nt) * 256 + m) * 128 + j];
    float s = bias;
#pragma unroll
    for (int ks = 0; ks < 32; ++ks) s += vals[ks];
    v += (s - v) * 0.5f;
    bool sp = v >= 1.f;
    l1s[(size_t)m * 1152 + n] = sp ? 1.f : 0.f;
    if (sp) v = 0.f;
  }
}

// fused tail: fc2 + LIF + fc3 + LIF + mean over T. One block per batch b.
// [R13 monolithic form restored]
__global__ __launch_bounds__(512) void tail(const float* __restrict__ l1s,
                                            const float* __restrict__ w2t,
                                            const float* __restrict__ b2,
                                            const float* __restrict__ w3,
                                            const float* __restrict__ b3,
                                            float* __restrict__ out) {
  __shared__ float sx[8][1152];                     // l1 spikes for this b (36 KB)
  __shared__ float part2[4][8][128];                // k-chunk partials (16 KB)
  __shared__ float s2[8][128];                      // l2 spikes
  __shared__ float y3[7][8];
  const int b = blockIdx.x;
  const int tid = threadIdx.x;
  for (int i = tid; i < 9216; i += 512) {
    int t = i / 1152, k = i - t * 1152;
    sx[t][k] = l1s[(size_t)(t * 32 + b) * 1152 + k];
  }
  __syncthreads();
  const int o = tid & 127, h = tid >> 7;            // h: 4-way K split
  float p[8];
#pragma unroll
  for (int t = 0; t < 8; ++t) p[t] = 0.f;
#pragma unroll 8
  for (int kk = 0; kk < 288; ++kk) {
    int k = h * 288 + kk;
    float wv = w2t[k * 128 + o];
#pragma unroll
    for (int t = 0; t < 8; ++t) p[t] += sx[t][k] * wv;
  }
#pragma unroll
  for (int t = 0; t < 8; ++t) part2[h][t][o] = p[t];
  __syncthreads();
  if (tid < 128) {
    float v = 0.f;
#pragma unroll
    for (int t = 0; t < 8; ++t) {
      float xx = part2[0][t][o] + part2[1][t][o] + part2[2][t][o] + part2[3][t][o] + b2[o];
      v += (xx - v) * 0.5f;
      bool s = v >= 1.f;
      s2[t][o] = s ? 1.f : 0.f;
      if (s) v = 0.f;
    }
  }
  __syncthreads();
  if (tid < 56) {
    int oo = tid >> 3, t = tid & 7;
    float d = 0.f;
    for (int k = 0; k < 128; ++k) d += s2[t][k] * w3[oo * 128 + k];
    y3[oo][t] = d + b3[oo];
  }
  __syncthreads();
  if (tid < 7) {
    float v = 0.f, a = 0.f;
#pragma unroll
    for (int t = 0; t < 8; ++t) {
      float xx = y3[tid][t];
      v += (xx - v) * 0.5f;
      bool s = v >= 1.f;
      a += s ? 1.f : 0.f;
      if (s) v = 0.f;
    }
    out[b * 7 + tid] = a * 0.125f;
  }
}

// ---------------------------------------------------------------------------
extern "C" void kernel_launch(void* const* d_in, const int* in_sizes, int n_in,
                              void* d_out, int out_size, void* d_ws, size_t ws_size,
                              hipStream_t stream) {
  const float* x       = (const float*)d_in[0];
  const float* conv1_w = (const float*)d_in[1];
  const float* conv1_b = (const float*)d_in[2];
  const float* bn1_g   = (const float*)d_in[3];
  const float* bn1_b   = (const float*)d_in[4];
  const float* bn1_m   = (const float*)d_in[5];
  const float* bn1_v   = (const float*)d_in[6];
  const float* conv2_w = (const float*)d_in[7];
  const float* conv2_b = (const float*)d_in[8];
  const float* bn2_g   = (const float*)d_in[9];
  const float* bn2_b   = (const float*)d_in[10];
  const float* bn2_m   = (const float*)d_in[11];
  const float* bn2_v   = (const float*)d_in[12];
  const float* fc1_w   = (const float*)d_in[13];
  const float* fc1_b   = (const float*)d_in[14];
  const float* fc2_w   = (const float*)d_in[15];
  const float* fc2_b   = (const float*)d_in[16];
  const float* fc3_w   = (const float*)d_in[17];
  const float* fc3_b   = (const float*)d_in[18];

  char* ws = (char*)d_ws;
  short* p1pad = (short*)(ws + OFF_P1);
  float* part  = (float*)(ws + OFF_PART);
  short* wt_hi = (short*)(ws + OFF_WT);
  short* wt_lo = wt_hi + 147456;
  short* p2    = (short*)(ws + OFF_P2);
  float* w2t   = (float*)(ws + OFF_W2T);
  float* l1s   = (float*)(ws + OFF_L1S);
  float* out   = (float*)d_out;

  prep_conv1<<<11968, 256, 0, stream>>>(conv2_w, fc2_w, wt_hi, wt_lo, w2t, (uint4*)p1pad,
                                        x, conv1_w, conv1_b, bn1_g, bn1_b, bn1_m, bn1_v, p1pad);
  conv2_gemm<<<dim3(32, 18), 256, 0, stream>>>(p1pad, wt_hi, wt_lo, conv2_b, bn2_g, bn2_b, bn2_m, bn2_v, p2);
  fc1_gemm<<<dim3(18, 32), 512, 0, stream>>>(p2, fc1_w, part);
  fc1_reduce_lif<<<288, 128, 0, stream>>>(part, fc1_b, l1s);
  tail<<<32, 512, 0, stream>>>(l1s, w2t, fc2_b, fc3_w, fc3_b, out);
}

// Round 12
// 331.800 us; speedup vs baseline: 1.0037x; 1.0037x over previous
//
#include <hip/hip_runtime.h>
#include <hip/hip_bf16.h>

// ---------------------------------------------------------------------------
// SJCSNN: conv1+bn1 -> IF -> pool -> conv2+bn2 -> IF -> pool -> fc1 -> LIF ->
//         fc2 -> LIF -> fc3 -> LIF -> mean over T.  T=8, B=32.
// Spikes are binary => exact in bf16 => MFMA with hi/lo-split fp32 weights
// gives fp32-identical threshold decisions (absmax == 0.0 across rounds).
// conv2 (FROZEN, ~101us): R5 1-phase gload_lds + R11 grid swap (b fastest).
// R12 (kept): fc1_reduce 32-wide load ILP; prep+conv1 merged; tail unroll 8.
// R13 (kept, best 328.1): fc1_gemm N-retile 64 -> 576 blocks (full machine).
// R14/R15 (REVERTED): tail fusion/split experiments null or worse.
// R16 (REVERTED): 2-deep fc1 B-prefetch -5us WORSE -> B latency was already
//   covered by R9's 1-deep; fc1 residual is barrier-serialized staging.
// R17: conv1 weight reuse: 8 sp per block (4 iters x 2), w1/bn loaded ONCE
//   per block -> 2304 blocks (was 9216), redundant param traffic 64->16MB.
//   Per-(sp,b,c) math, LIF chains, store addresses verbatim => bit-exact.
// ---------------------------------------------------------------------------

typedef float  f32x4  __attribute__((ext_vector_type(4)));
typedef __bf16 bf16x8 __attribute__((ext_vector_type(8)));

#define T_STEPS 8

// ---- workspace layout (bytes) ----
static const size_t OFF_P1    = 0;                  // p1pad 44,302,336 (dead after conv2)
static const size_t OFF_PART  = 0;                  // fc1 partials 37,748,736 (reuse)
static const size_t OFF_WT    = 44302336;           // 1,179,648 (hi+lo conv2 weights)
static const size_t OFF_P2    = 45481984;           // 9,437,184
static const size_t OFF_W2T   = 54919168;           //   589,824
static const size_t OFF_L1S   = 55508992;           // 1,179,648  (end 56,688,640)

__device__ __forceinline__ unsigned short bf16_rne(float f) {
  unsigned u = __builtin_bit_cast(unsigned, f);
  u += 0x7FFFu + ((u >> 16) & 1u);
  return (unsigned short)(u >> 16);
}
__device__ __forceinline__ float bf16_to_f(unsigned short h) {
  unsigned u = ((unsigned)h) << 16;
  return __builtin_bit_cast(float, u);
}

// packed split: two fp32 -> packed hi-bf16 pair + packed lo-bf16 pair.
__device__ __forceinline__ void split_pair(float f0, float f1, unsigned& hi, unsigned& lo) {
  __hip_bfloat162 h2 = __float22bfloat162_rn(make_float2(f0, f1));
  unsigned uh; __builtin_memcpy(&uh, &h2, 4);
  float g0 = __builtin_bit_cast(float, uh << 16);
  float g1 = __builtin_bit_cast(float, uh & 0xFFFF0000u);
  __hip_bfloat162 l2 = __float22bfloat162_rn(make_float2(f0 - g0, f1 - g1));
  unsigned ul; __builtin_memcpy(&ul, &l2, 4);
  hi = uh;
  lo = ul;
}

__device__ __forceinline__ void lds_load16(const void* g, void* l) {
  auto* gp = reinterpret_cast<const __attribute__((address_space(1))) unsigned int*>(
      reinterpret_cast<uintptr_t>(g));
  auto* lp = reinterpret_cast<__attribute__((address_space(3))) unsigned int*>(
      reinterpret_cast<uintptr_t>(l));
  __builtin_amdgcn_global_load_lds(gp, lp, 16, 0, 0);
}

// ---------------------------------------------------------------------------
// merged prep + conv1.  Blocks [0,2752): prep (conv2_w hi/lo split, fc2_w
// transpose, p1pad border zero).  Blocks [2752,5056): conv1+bn1 -> IF(T) ->
// pool; R17: 8 spatial positions per 256-thread block (4 iters x 2 halves),
// weights/bn loaded once per block.
__global__ __launch_bounds__(256) void prep_conv1(
    const float* __restrict__ conv2_w, const float* __restrict__ fc2_w,
    short* __restrict__ wt_hi, short* __restrict__ wt_lo, float* __restrict__ w2t,
    uint4* __restrict__ p1pad4,
    const float* __restrict__ x, const float* __restrict__ w1, const float* __restrict__ b1,
    const float* __restrict__ g1, const float* __restrict__ be1, const float* __restrict__ m1,
    const float* __restrict__ vv1, short* __restrict__ p1) {
  __shared__ float patch[2][16];
  const int bx = blockIdx.x;
  if (bx < 2752) {
    // ---- prep ----
    int i = bx * 256 + threadIdx.x;                  // < 704512
    if (i < 147456) {
      int tap = i >> 14;
      int oc  = (i >> 7) & 127;
      int ic  = i & 127;
      float wv = conv2_w[oc * 1152 + ic * 9 + tap];
      unsigned short h = bf16_rne(wv);
      wt_hi[i] = (short)h;
      wt_lo[i] = (short)bf16_rne(wv - bf16_to_f(h));
    } else if (i < 294912) {
      int j = i - 147456;
      int o = j & 127, k = j >> 7;
      w2t[j] = fc2_w[o * 1152 + k];
    } else {
      int k = i - 294912;                            // 256 tb x 100 border pos x 16 uint4
      int tb = k / 1600;
      int rem = k - tb * 1600;
      int pos = rem >> 4, c8 = rem & 15;
      int y, xx;
      if (pos < 26)      { y = 0;  xx = pos; }
      else if (pos < 52) { y = 25; xx = pos - 26; }
      else { int jj = pos - 52; y = 1 + (jj >> 1); xx = (jj & 1) * 25; }
      p1pad4[(tb * 676 + y * 26 + xx) * 16 + c8] = make_uint4(0u, 0u, 0u, 0u);
    }
    return;
  }
  // ---- conv1: bid in [0,2304): b = bid/72, sp-group = bid%72 (8 sp each) --
  const int bid  = bx - 2752;
  const int b    = bid / 72;
  const int grp  = bid - b * 72;
  const int half = threadIdx.x >> 7;                 // 0/1
  const int c    = threadIdx.x & 127;
  float w[9];
#pragma unroll
  for (int i = 0; i < 9; ++i) w[i] = w1[c * 9 + i];
  float scale = g1[c] * rsqrtf(vv1[c] + 1e-5f);
  float shift = (b1[c] - m1[c]) * scale + be1[c];
#pragma unroll 1
  for (int g = 0; g < 4; ++g) {
    const int sp = grp * 8 + g * 2 + half;           // 0..575
    const int oy = sp / 24, ox = sp % 24;
    __syncthreads();                                 // patch safe to overwrite
    if (c < 16) {
      int py = c >> 2, px = c & 3;
      int iy = 2 * oy - 1 + py, ix = 2 * ox - 1 + px;
      float v = 0.f;
      if (iy >= 0 && iy < 48 && ix >= 0 && ix < 48) v = x[b * 2304 + iy * 48 + ix];
      patch[half][c] = v;
    }
    __syncthreads();
    float h[4];
#pragma unroll
    for (int p = 0; p < 4; ++p) {
      int py = p >> 1, px = p & 1;
      float s = 0.f;
#pragma unroll
      for (int dy = 0; dy < 3; ++dy)
#pragma unroll
        for (int dx = 0; dx < 3; ++dx) s += patch[half][(py + dy) * 4 + (px + dx)] * w[dy * 3 + dx];
      h[p] = s * scale + shift;
    }
    float va = 0.f, vb = 0.f, vc = 0.f, vd = 0.f;
    size_t base = ((size_t)b * 676 + (size_t)(1 + oy) * 26 + (1 + ox)) * 128 + c;
#pragma unroll
    for (int t = 0; t < T_STEPS; ++t) {
      va += h[0]; vb += h[1]; vc += h[2]; vd += h[3];
      bool s0 = va >= 1.f, s1 = vb >= 1.f, s2 = vc >= 1.f, s3 = vd >= 1.f;
      p1[base + (size_t)t * (32 * 676 * 128)] = (s0 | s1 | s2 | s3) ? (short)0x3F80 : (short)0;
      if (s0) va = 0.f; if (s1) vb = 0.f; if (s2) vc = 0.f; if (s3) vd = 0.f;
    }
  }
}

// conv2 implicit-im2col MFMA GEMM, 256x128 block tile (4 waves x 128x64),
// fused bn2 + IF(T) + 2x2 maxpool epilogue. [FROZEN: R5 structure + R11 swap]
__global__ __launch_bounds__(256, 2) void conv2_gemm(
    const short* __restrict__ p1pad, const short* __restrict__ wt_hi, const short* __restrict__ wt_lo,
    const float* __restrict__ conv2_b, const float* __restrict__ bn2_g, const float* __restrict__ bn2_b,
    const float* __restrict__ bn2_m, const float* __restrict__ bn2_v, short* __restrict__ p2) {
  __shared__ __align__(16) short lds[32768];        // A:16384  Bh:8192  Bl:8192 shorts (64 KB)
  short* ldsA  = lds;
  short* ldsBh = lds + 16384;
  short* ldsBl = lds + 24576;

  const int tid = threadIdx.x;
  const int lane = tid & 63;
  const int w = tid >> 6;                           // 0..3
  const int wm = w & 1, wn = w >> 1;
  const int b  = blockIdx.x;                        // b fastest -> XCD = b%8
  const int sp = blockIdx.y;                        // 0..17 spatial tile
  const int gy = sp / 3;
  const int gx = sp - gy * 3;

  const int g = (lane & 7) ^ (lane >> 3);
  int rowofsA[8], bofs[4];
#pragma unroll
  for (int j = 0; j < 8; ++j) {
    int r = w * 64 + j * 8 + (lane >> 3);
    int t = r >> 5, iy = (r >> 3) & 3, ix = r & 7;
    rowofsA[j] = (((t * 32 + b) * 676) + (4 * gy + iy) * 26 + (8 * gx + ix)) * 128 + g * 8;
  }
#pragma unroll
  for (int j = 0; j < 4; ++j) {
    int n = w * 32 + j * 8 + (lane >> 3);
    bofs[j] = n * 128 + g * 8;
  }

  f32x4 acc[8][4];
#pragma unroll
  for (int mi = 0; mi < 8; ++mi)
#pragma unroll
    for (int ni = 0; ni < 4; ++ni) acc[mi][ni] = (f32x4){0.f, 0.f, 0.f, 0.f};

#pragma unroll 1
  for (int s = 0; s < 18; ++s) {
    const int tap = s >> 1;
    const int kk = (s & 1) << 6;
    const int tapoff = ((tap / 3) * 26 + (tap % 3)) * 128;
    __syncthreads();
#pragma unroll
    for (int j = 0; j < 8; ++j) {
      lds_load16(p1pad + rowofsA[j] + tapoff + kk, ldsA + (w * 64 + j * 8) * 64 + lane * 8);
    }
    const int wtoff = tap * 16384 + kk;
#pragma unroll
    for (int j = 0; j < 4; ++j) {
      lds_load16(wt_hi + wtoff + bofs[j], ldsBh + (w * 32 + j * 8) * 64 + lane * 8);
      lds_load16(wt_lo + wtoff + bofs[j], ldsBl + (w * 32 + j * 8) * 64 + lane * 8);
    }
    __syncthreads();
#pragma unroll
    for (int ks = 0; ks < 2; ++ks) {
      const int cch = ks * 4 + (lane >> 4);
      bf16x8 a[8], bh[4], bl[4];
#pragma unroll
      for (int i = 0; i < 8; ++i) {
        int r = wm * 128 + i * 16 + (lane & 15);
        a[i] = *(const bf16x8*)(ldsA + r * 64 + ((cch ^ (r & 7)) * 8));
      }
#pragma unroll
      for (int i = 0; i < 4; ++i) {
        int n = wn * 64 + i * 16 + (lane & 15);
        bh[i] = *(const bf16x8*)(ldsBh + n * 64 + ((cch ^ (n & 7)) * 8));
        bl[i] = *(const bf16x8*)(ldsBl + n * 64 + ((cch ^ (n & 7)) * 8));
      }
#pragma unroll
      for (int mi = 0; mi < 8; ++mi)
#pragma unroll
        for (int ni = 0; ni < 4; ++ni) {
          acc[mi][ni] = __builtin_amdgcn_mfma_f32_16x16x32_bf16(a[mi], bh[ni], acc[mi][ni], 0, 0, 0);
          acc[mi][ni] = __builtin_amdgcn_mfma_f32_16x16x32_bf16(a[mi], bl[ni], acc[mi][ni], 0, 0, 0);
        }
    }
  }

  // ---- fused epilogue: 4 quarters of 64 rows (= t-pairs, sequential in t).
  float sc[4], sh[4];
#pragma unroll
  for (int ni = 0; ni < 4; ++ni) {
    int oc = wn * 64 + ni * 16 + (lane & 15);
    sc[ni] = bn2_g[oc] * rsqrtf(bn2_v[oc] + 1e-5f);
    sh[ni] = (conv2_b[oc] - bn2_m[oc]) * sc[ni] + bn2_b[oc];
  }
  float* ybuf = (float*)lds;                        // 64 rows x stride 132 floats
  const int S = 132;
  float v[32];
#pragma unroll
  for (int q = 0; q < 32; ++q) v[q] = 0.f;
  unsigned short* p2u = (unsigned short*)p2;
  __syncthreads();
#pragma unroll
  for (int q = 0; q < 4; ++q) {                     // FULLY UNROLLED (acc idx const)
    if (wm == (q >> 1)) {
      const int mib = (q & 1) * 4;
#pragma unroll
      for (int ml = 0; ml < 4; ++ml)
#pragma unroll
        for (int ni = 0; ni < 4; ++ni)
#pragma unroll
          for (int r = 0; r < 4; ++r) {
            int lam = ml * 16 + ((lane >> 4) << 2) + r;
            int col = wn * 64 + ni * 16 + (lane & 15);
            ybuf[lam * S + col] = acc[mib + ml][ni][r] * sc[ni] + sh[ni];
          }
    }
    __syncthreads();
    if (tid < 128) {
      const int oc = tid;
#pragma unroll
      for (int tt = 0; tt < 2; ++tt) {
        int t = 2 * q + tt;
#pragma unroll
        for (int pooly = 0; pooly < 2; ++pooly) {
          unsigned short ov[4];
#pragma unroll
          for (int poolx = 0; poolx < 4; ++poolx) {
            bool any = false;
#pragma unroll
            for (int ry = 0; ry < 2; ++ry)
#pragma unroll
              for (int rx = 0; rx < 2; ++rx) {
                int iy = 2 * pooly + ry, ix = 2 * poolx + rx;
                float xx = ybuf[(tt * 32 + iy * 8 + ix) * S + oc];
                int qi = iy * 8 + ix;
                v[qi] += xx;
                bool ss = v[qi] >= 1.f;
                any |= ss;
                if (ss) v[qi] = 0.f;
              }
            ov[poolx] = any ? (unsigned short)0x3F80 : (unsigned short)0;
          }
          ushort4 o4; o4.x = ov[0]; o4.y = ov[1]; o4.z = ov[2]; o4.w = ov[3];
          *(ushort4*)(p2u + ((size_t)(t * 32 + b) * 128 + oc) * 144 + (2 * gy + pooly) * 12 + 4 * gx) = o4;
        }
      }
    }
    __syncthreads();
  }
}

// fc1: M=256, N=1152, K=18432 split 32 ways.  [R13 state: N-tiles of 64,
// grid 18x32 = 576 blocks, LDS 48KB, acc[4][2], 1-deep B prefetch]
__global__ __launch_bounds__(512) void fc1_gemm(const short* __restrict__ p2,
                                                const float* __restrict__ fc1_w,
                                                float* __restrict__ part) {
  __shared__ __align__(16) short lds[24576];        // A:16384  Bh:4096  Bl:4096 (48 KB)
  short* ldsA = lds;
  short* ldsBh = lds + 16384;
  short* ldsBl = lds + 20480;

  const int tid = threadIdx.x;
  const int lane = tid & 63;
  const int w = tid >> 6;                           // 0..7
  const int wm = w & 3, wn = w >> 2;                // wm: 64-row quarter; wn: 32-col half
  const int nt2 = blockIdx.x;                       // 0..17 N-tile of 64 cols
  const int n0 = nt2 * 64;
  const int kb = blockIdx.y * 576;

  const int g = (lane & 7) ^ (lane >> 3);
  int aofs[4];
#pragma unroll
  for (int j = 0; j < 4; ++j) {
    int r = w * 32 + j * 8 + (lane >> 3);
    aofs[j] = r * 18432 + g * 8;
  }
  const int bn = tid >> 3;                          // 0..63 B row
  const int c0 = tid & 7;                           // chunk of 8 floats
  const float* wrow = fc1_w + (size_t)(n0 + bn) * 18432 + c0 * 8;
  const int bpos = (c0 ^ (bn & 7)) * 8;

  f32x4 acc[4][2];
#pragma unroll
  for (int mi = 0; mi < 4; ++mi)
#pragma unroll
    for (int ni = 0; ni < 2; ++ni) acc[mi][ni] = (f32x4){0.f, 0.f, 0.f, 0.f};

  // prologue: B regs for substage 0
  float4 q0, q1;
  {
    const float4* wp = (const float4*)(wrow + kb);
    q0 = wp[0]; q1 = wp[1];
  }

#pragma unroll 1
  for (int s = 0; s < 9; ++s) {
    const int koff = kb + s * 64;
    __syncthreads();
#pragma unroll
    for (int j = 0; j < 4; ++j) {
      lds_load16(p2 + aofs[j] + koff, ldsA + (w * 32 + j * 8) * 64 + lane * 8);
    }
    {
      unsigned h0, h1, h2, h3, l0, l1, l2, l3;
      split_pair(q0.x, q0.y, h0, l0);
      split_pair(q0.z, q0.w, h1, l1);
      split_pair(q1.x, q1.y, h2, l2);
      split_pair(q1.z, q1.w, h3, l3);
      uint4 H; H.x = h0; H.y = h1; H.z = h2; H.w = h3;
      uint4 L; L.x = l0; L.y = l1; L.z = l2; L.w = l3;
      *(uint4*)(ldsBh + bn * 64 + bpos) = H;
      *(uint4*)(ldsBl + bn * 64 + bpos) = L;
    }
    if (s < 8) {                                    // prefetch next B (consumed next iter)
      const float4* wp = (const float4*)(wrow + koff + 64);
      q0 = wp[0]; q1 = wp[1];
    }
    __builtin_amdgcn_sched_barrier(0);              // keep prefetch above the barrier
    __syncthreads();
#pragma unroll
    for (int ks = 0; ks < 2; ++ks) {
      bf16x8 a[4], bh[2], bl[2];
      const int cch = ks * 4 + (lane >> 4);
#pragma unroll
      for (int i = 0; i < 4; ++i) {
        int r = wm * 64 + i * 16 + (lane & 15);
        a[i] = *(const bf16x8*)(ldsA + r * 64 + ((cch ^ (r & 7)) * 8));
      }
#pragma unroll
      for (int i = 0; i < 2; ++i) {
        int n = wn * 32 + i * 16 + (lane & 15);
        bh[i] = *(const bf16x8*)(ldsBh + n * 64 + ((cch ^ (n & 7)) * 8));
        bl[i] = *(const bf16x8*)(ldsBl + n * 64 + ((cch ^ (n & 7)) * 8));
      }
#pragma unroll
      for (int mi = 0; mi < 4; ++mi)
#pragma unroll
        for (int ni = 0; ni < 2; ++ni) {
          acc[mi][ni] = __builtin_amdgcn_mfma_f32_16x16x32_bf16(a[mi], bh[ni], acc[mi][ni], 0, 0, 0);
          acc[mi][ni] = __builtin_amdgcn_mfma_f32_16x16x32_bf16(a[mi], bl[ni], acc[mi][ni], 0, 0, 0);
        }
    }
  }
  const int nt = nt2 >> 1;                          // 128-col tile for part layout
  const int jbase = (nt2 & 1) * 64;
  const size_t pbase = (size_t)(blockIdx.y * 9 + nt) * 32768;
#pragma unroll
  for (int ni = 0; ni < 2; ++ni) {
    int j = jbase + wn * 32 + ni * 16 + (lane & 15);
#pragma unroll
    for (int mi = 0; mi < 4; ++mi) {
#pragma unroll
      for (int r = 0; r < 4; ++r) {
        int m = wm * 64 + mi * 16 + ((lane >> 4) << 2) + r;
        part[pbase + (size_t)m * 128 + j] = acc[mi][ni][r];
      }
    }
  }
}

// split-K reduce + bias + LIF over T, writing l1 spikes.  [R12/R13 state]
__global__ __launch_bounds__(128) void fc1_reduce_lif(const float* __restrict__ part,
                                                      const float* __restrict__ fc1_b,
                                                      float* __restrict__ l1s) {
  int i = blockIdx.x * 128 + threadIdx.x;           // < 36864 : (b, n)
  int b = i / 1152, n = i - b * 1152;
  int nt = n >> 7, j = n & 127;
  float bias = fc1_b[n];
  float v = 0.f;
#pragma unroll
  for (int t = 0; t < T_STEPS; ++t) {
    int m = t * 32 + b;
    float vals[32];
#pragma unroll
    for (int ks = 0; ks < 32; ++ks)
      vals[ks] = part[(((size_t)ks * 9 + nt) * 256 + m) * 128 + j];
    float s = bias;
#pragma unroll
    for (int ks = 0; ks < 32; ++ks) s += vals[ks];
    v += (s - v) * 0.5f;
    bool sp = v >= 1.f;
    l1s[(size_t)m * 1152 + n] = sp ? 1.f : 0.f;
    if (sp) v = 0.f;
  }
}

// fused tail: fc2 + LIF + fc3 + LIF + mean over T. One block per batch b.
// [R13 monolithic form]
__global__ __launch_bounds__(512) void tail(const float* __restrict__ l1s,
                                            const float* __restrict__ w2t,
                                            const float* __restrict__ b2,
                                            const float* __restrict__ w3,
                                            const float* __restrict__ b3,
                                            float* __restrict__ out) {
  __shared__ float sx[8][1152];                     // l1 spikes for this b (36 KB)
  __shared__ float part2[4][8][128];                // k-chunk partials (16 KB)
  __shared__ float s2[8][128];                      // l2 spikes
  __shared__ float y3[7][8];
  const int b = blockIdx.x;
  const int tid = threadIdx.x;
  for (int i = tid; i < 9216; i += 512) {
    int t = i / 1152, k = i - t * 1152;
    sx[t][k] = l1s[(size_t)(t * 32 + b) * 1152 + k];
  }
  __syncthreads();
  const int o = tid & 127, h = tid >> 7;            // h: 4-way K split
  float p[8];
#pragma unroll
  for (int t = 0; t < 8; ++t) p[t] = 0.f;
#pragma unroll 8
  for (int kk = 0; kk < 288; ++kk) {
    int k = h * 288 + kk;
    float wv = w2t[k * 128 + o];
#pragma unroll
    for (int t = 0; t < 8; ++t) p[t] += sx[t][k] * wv;
  }
#pragma unroll
  for (int t = 0; t < 8; ++t) part2[h][t][o] = p[t];
  __syncthreads();
  if (tid < 128) {
    float v = 0.f;
#pragma unroll
    for (int t = 0; t < 8; ++t) {
      float xx = part2[0][t][o] + part2[1][t][o] + part2[2][t][o] + part2[3][t][o] + b2[o];
      v += (xx - v) * 0.5f;
      bool s = v >= 1.f;
      s2[t][o] = s ? 1.f : 0.f;
      if (s) v = 0.f;
    }
  }
  __syncthreads();
  if (tid < 56) {
    int oo = tid >> 3, t = tid & 7;
    float d = 0.f;
    for (int k = 0; k < 128; ++k) d += s2[t][k] * w3[oo * 128 + k];
    y3[oo][t] = d + b3[oo];
  }
  __syncthreads();
  if (tid < 7) {
    float v = 0.f, a = 0.f;
#pragma unroll
    for (int t = 0; t < 8; ++t) {
      float xx = y3[tid][t];
      v += (xx - v) * 0.5f;
      bool s = v >= 1.f;
      a += s ? 1.f : 0.f;
      if (s) v = 0.f;
    }
    out[b * 7 + tid] = a * 0.125f;
  }
}

// ---------------------------------------------------------------------------
extern "C" void kernel_launch(void* const* d_in, const int* in_sizes, int n_in,
                              void* d_out, int out_size, void* d_ws, size_t ws_size,
                              hipStream_t stream) {
  const float* x       = (const float*)d_in[0];
  const float* conv1_w = (const float*)d_in[1];
  const float* conv1_b = (const float*)d_in[2];
  const float* bn1_g   = (const float*)d_in[3];
  const float* bn1_b   = (const float*)d_in[4];
  const float* bn1_m   = (const float*)d_in[5];
  const float* bn1_v   = (const float*)d_in[6];
  const float* conv2_w = (const float*)d_in[7];
  const float* conv2_b = (const float*)d_in[8];
  const float* bn2_g   = (const float*)d_in[9];
  const float* bn2_b   = (const float*)d_in[10];
  const float* bn2_m   = (const float*)d_in[11];
  const float* bn2_v   = (const float*)d_in[12];
  const float* fc1_w   = (const float*)d_in[13];
  const float* fc1_b   = (const float*)d_in[14];
  const float* fc2_w   = (const float*)d_in[15];
  const float* fc2_b   = (const float*)d_in[16];
  const float* fc3_w   = (const float*)d_in[17];
  const float* fc3_b   = (const float*)d_in[18];

  char* ws = (char*)d_ws;
  short* p1pad = (short*)(ws + OFF_P1);
  float* part  = (float*)(ws + OFF_PART);
  short* wt_hi = (short*)(ws + OFF_WT);
  short* wt_lo = wt_hi + 147456;
  short* p2    = (short*)(ws + OFF_P2);
  float* w2t   = (float*)(ws + OFF_W2T);
  float* l1s   = (float*)(ws + OFF_L1S);
  float* out   = (float*)d_out;

  prep_conv1<<<5056, 256, 0, stream>>>(conv2_w, fc2_w, wt_hi, wt_lo, w2t, (uint4*)p1pad,
                                       x, conv1_w, conv1_b, bn1_g, bn1_b, bn1_m, bn1_v, p1pad);
  conv2_gemm<<<dim3(32, 18), 256, 0, stream>>>(p1pad, wt_hi, wt_lo, conv2_b, bn2_g, bn2_b, bn2_m, bn2_v, p2);
  fc1_gemm<<<dim3(18, 32), 512, 0, stream>>>(p2, fc1_w, part);
  fc1_reduce_lif<<<288, 128, 0, stream>>>(part, fc1_b, l1s);
  tail<<<32, 512, 0, stream>>>(l1s, w2t, fc2_b, fc3_w, fc3_b, out);
}

// Round 13
// 328.812 us; speedup vs baseline: 1.0128x; 1.0091x over previous
//
#include <hip/hip_runtime.h>
#include <hip/hip_bf16.h>

// ---------------------------------------------------------------------------
// SJCSNN: conv1+bn1 -> IF -> pool -> conv2+bn2 -> IF -> pool -> fc1 -> LIF ->
//         fc2 -> LIF -> fc3 -> LIF -> mean over T.  T=8, B=32.
// Spikes are binary => exact in bf16 => MFMA with hi/lo-split fp32 weights
// gives fp32-identical threshold decisions (absmax == 0.0 across rounds).
// conv2 (FROZEN, ~101us): R5 1-phase gload_lds + R11 grid swap (b fastest).
// R12 (kept): fc1_reduce 32-wide load ILP; prep+conv1 merged; tail unroll 8.
// R13 (kept, best 328.1): fc1_gemm N-retile 64 -> 576 blocks (full machine).
// R14/R15/R16 (REVERTED): tail fusion/split null-or-worse; 2-deep B prefetch
//   worse (1-deep already covers).
// R17 (REVERTED, +3.7): conv1 8-sp grouping traded TLP for param reuse L1
//   already provided.
// R18: conv1 spike stores widened 2B -> 16B: LIF loop writes spikes to a
//   4KB LDS buffer (consecutive-c 2B/lane = 2-way aliasing, free), one
//   barrier, then each thread emits ONE coalesced uint4 (256B per (sp,t)
//   row; 8 scalar stores/thread -> 1 vector store). Same values, same
//   addresses => bit-exact.  Everything else = R13 verbatim.
// ---------------------------------------------------------------------------

typedef float  f32x4  __attribute__((ext_vector_type(4)));
typedef __bf16 bf16x8 __attribute__((ext_vector_type(8)));

#define T_STEPS 8

// ---- workspace layout (bytes) ----
static const size_t OFF_P1    = 0;                  // p1pad 44,302,336 (dead after conv2)
static const size_t OFF_PART  = 0;                  // fc1 partials 37,748,736 (reuse)
static const size_t OFF_WT    = 44302336;           // 1,179,648 (hi+lo conv2 weights)
static const size_t OFF_P2    = 45481984;           // 9,437,184
static const size_t OFF_W2T   = 54919168;           //   589,824
static const size_t OFF_L1S   = 55508992;           // 1,179,648  (end 56,688,640)

__device__ __forceinline__ unsigned short bf16_rne(float f) {
  unsigned u = __builtin_bit_cast(unsigned, f);
  u += 0x7FFFu + ((u >> 16) & 1u);
  return (unsigned short)(u >> 16);
}
__device__ __forceinline__ float bf16_to_f(unsigned short h) {
  unsigned u = ((unsigned)h) << 16;
  return __builtin_bit_cast(float, u);
}

// packed split: two fp32 -> packed hi-bf16 pair + packed lo-bf16 pair.
__device__ __forceinline__ void split_pair(float f0, float f1, unsigned& hi, unsigned& lo) {
  __hip_bfloat162 h2 = __float22bfloat162_rn(make_float2(f0, f1));
  unsigned uh; __builtin_memcpy(&uh, &h2, 4);
  float g0 = __builtin_bit_cast(float, uh << 16);
  float g1 = __builtin_bit_cast(float, uh & 0xFFFF0000u);
  __hip_bfloat162 l2 = __float22bfloat162_rn(make_float2(f0 - g0, f1 - g1));
  unsigned ul; __builtin_memcpy(&ul, &l2, 4);
  hi = uh;
  lo = ul;
}

__device__ __forceinline__ void lds_load16(const void* g, void* l) {
  auto* gp = reinterpret_cast<const __attribute__((address_space(1))) unsigned int*>(
      reinterpret_cast<uintptr_t>(g));
  auto* lp = reinterpret_cast<__attribute__((address_space(3))) unsigned int*>(
      reinterpret_cast<uintptr_t>(l));
  __builtin_amdgcn_global_load_lds(gp, lp, 16, 0, 0);
}

// ---------------------------------------------------------------------------
// merged prep + conv1.  Blocks [0,2752): prep (conv2_w hi/lo split, fc2_w
// transpose, p1pad border zero).  Blocks [2752,11968): conv1+bn1 -> IF(T) ->
// pool, 2 spatial positions per 256-thread block; R18: spike stores staged
// in LDS and written as one uint4 per thread (coalesced 256B rows).
__global__ __launch_bounds__(256) void prep_conv1(
    const float* __restrict__ conv2_w, const float* __restrict__ fc2_w,
    short* __restrict__ wt_hi, short* __restrict__ wt_lo, float* __restrict__ w2t,
    uint4* __restrict__ p1pad4,
    const float* __restrict__ x, const float* __restrict__ w1, const float* __restrict__ b1,
    const float* __restrict__ g1, const float* __restrict__ be1, const float* __restrict__ m1,
    const float* __restrict__ vv1, short* __restrict__ p1) {
  __shared__ float patch[2][16];
  __shared__ __align__(16) unsigned short spike[2][8][128];   // 4 KB
  const int bx = blockIdx.x;
  if (bx < 2752) {
    // ---- prep ----
    int i = bx * 256 + threadIdx.x;                  // < 704512
    if (i < 147456) {
      int tap = i >> 14;
      int oc  = (i >> 7) & 127;
      int ic  = i & 127;
      float wv = conv2_w[oc * 1152 + ic * 9 + tap];
      unsigned short h = bf16_rne(wv);
      wt_hi[i] = (short)h;
      wt_lo[i] = (short)bf16_rne(wv - bf16_to_f(h));
    } else if (i < 294912) {
      int j = i - 147456;
      int o = j & 127, k = j >> 7;
      w2t[j] = fc2_w[o * 1152 + k];
    } else {
      int k = i - 294912;                            // 256 tb x 100 border pos x 16 uint4
      int tb = k / 1600;
      int rem = k - tb * 1600;
      int pos = rem >> 4, c8 = rem & 15;
      int y, xx;
      if (pos < 26)      { y = 0;  xx = pos; }
      else if (pos < 52) { y = 25; xx = pos - 26; }
      else { int jj = pos - 52; y = 1 + (jj >> 1); xx = (jj & 1) * 25; }
      p1pad4[(tb * 676 + y * 26 + xx) * 16 + c8] = make_uint4(0u, 0u, 0u, 0u);
    }
    return;
  }
  // ---- conv1: bid in [0,9216): b = bid/288, sp-pair = bid%288 ----
  const int bid  = bx - 2752;
  const int b    = bid / 288;
  const int spp  = bid - b * 288;
  const int half = threadIdx.x >> 7;                 // 0/1: which sp of the pair
  const int sp   = spp * 2 + half;                   // 0..575
  const int c    = threadIdx.x & 127;
  const int oy = sp / 24, ox = sp % 24;
  if (c < 16) {
    int py = c >> 2, px = c & 3;
    int iy = 2 * oy - 1 + py, ix = 2 * ox - 1 + px;
    float v = 0.f;
    if (iy >= 0 && iy < 48 && ix >= 0 && ix < 48) v = x[b * 2304 + iy * 48 + ix];
    patch[half][c] = v;
  }
  __syncthreads();
  float w[9];
#pragma unroll
  for (int i = 0; i < 9; ++i) w[i] = w1[c * 9 + i];
  float scale = g1[c] * rsqrtf(vv1[c] + 1e-5f);
  float shift = (b1[c] - m1[c]) * scale + be1[c];
  float h[4];
#pragma unroll
  for (int p = 0; p < 4; ++p) {
    int py = p >> 1, px = p & 1;
    float s = 0.f;
#pragma unroll
    for (int dy = 0; dy < 3; ++dy)
#pragma unroll
      for (int dx = 0; dx < 3; ++dx) s += patch[half][(py + dy) * 4 + (px + dx)] * w[dy * 3 + dx];
    h[p] = s * scale + shift;
  }
  float va = 0.f, vb = 0.f, vc = 0.f, vd = 0.f;
#pragma unroll
  for (int t = 0; t < T_STEPS; ++t) {
    va += h[0]; vb += h[1]; vc += h[2]; vd += h[3];
    bool s0 = va >= 1.f, s1 = vb >= 1.f, s2 = vc >= 1.f, s3 = vd >= 1.f;
    spike[half][t][c] = (s0 | s1 | s2 | s3) ? (unsigned short)0x3F80 : (unsigned short)0;
    if (s0) va = 0.f; if (s1) vb = 0.f; if (s2) vc = 0.f; if (s3) vd = 0.f;
  }
  __syncthreads();
  // widened store: tid -> (half, t, 16B chunk); one uint4 per thread.
  {
    const int h2 = threadIdx.x >> 7;
    const int t  = (threadIdx.x >> 4) & 7;
    const int ch = threadIdx.x & 15;
    const int sp2 = spp * 2 + h2;
    const int oy2 = sp2 / 24, ox2 = sp2 % 24;
    size_t rowbase = ((size_t)b * 676 + (size_t)(1 + oy2) * 26 + (1 + ox2)) * 128 + ch * 8;
    uint4 v4 = *(const uint4*)&spike[h2][t][ch * 8];
    *(uint4*)((unsigned short*)p1 + rowbase + (size_t)t * (32 * 676 * 128)) = v4;
  }
}

// conv2 implicit-im2col MFMA GEMM, 256x128 block tile (4 waves x 128x64),
// fused bn2 + IF(T) + 2x2 maxpool epilogue. [FROZEN: R5 structure + R11 swap]
__global__ __launch_bounds__(256, 2) void conv2_gemm(
    const short* __restrict__ p1pad, const short* __restrict__ wt_hi, const short* __restrict__ wt_lo,
    const float* __restrict__ conv2_b, const float* __restrict__ bn2_g, const float* __restrict__ bn2_b,
    const float* __restrict__ bn2_m, const float* __restrict__ bn2_v, short* __restrict__ p2) {
  __shared__ __align__(16) short lds[32768];        // A:16384  Bh:8192  Bl:8192 shorts (64 KB)
  short* ldsA  = lds;
  short* ldsBh = lds + 16384;
  short* ldsBl = lds + 24576;

  const int tid = threadIdx.x;
  const int lane = tid & 63;
  const int w = tid >> 6;                           // 0..3
  const int wm = w & 1, wn = w >> 1;
  const int b  = blockIdx.x;                        // b fastest -> XCD = b%8
  const int sp = blockIdx.y;                        // 0..17 spatial tile
  const int gy = sp / 3;
  const int gx = sp - gy * 3;

  const int g = (lane & 7) ^ (lane >> 3);
  int rowofsA[8], bofs[4];
#pragma unroll
  for (int j = 0; j < 8; ++j) {
    int r = w * 64 + j * 8 + (lane >> 3);
    int t = r >> 5, iy = (r >> 3) & 3, ix = r & 7;
    rowofsA[j] = (((t * 32 + b) * 676) + (4 * gy + iy) * 26 + (8 * gx + ix)) * 128 + g * 8;
  }
#pragma unroll
  for (int j = 0; j < 4; ++j) {
    int n = w * 32 + j * 8 + (lane >> 3);
    bofs[j] = n * 128 + g * 8;
  }

  f32x4 acc[8][4];
#pragma unroll
  for (int mi = 0; mi < 8; ++mi)
#pragma unroll
    for (int ni = 0; ni < 4; ++ni) acc[mi][ni] = (f32x4){0.f, 0.f, 0.f, 0.f};

#pragma unroll 1
  for (int s = 0; s < 18; ++s) {
    const int tap = s >> 1;
    const int kk = (s & 1) << 6;
    const int tapoff = ((tap / 3) * 26 + (tap % 3)) * 128;
    __syncthreads();
#pragma unroll
    for (int j = 0; j < 8; ++j) {
      lds_load16(p1pad + rowofsA[j] + tapoff + kk, ldsA + (w * 64 + j * 8) * 64 + lane * 8);
    }
    const int wtoff = tap * 16384 + kk;
#pragma unroll
    for (int j = 0; j < 4; ++j) {
      lds_load16(wt_hi + wtoff + bofs[j], ldsBh + (w * 32 + j * 8) * 64 + lane * 8);
      lds_load16(wt_lo + wtoff + bofs[j], ldsBl + (w * 32 + j * 8) * 64 + lane * 8);
    }
    __syncthreads();
#pragma unroll
    for (int ks = 0; ks < 2; ++ks) {
      const int cch = ks * 4 + (lane >> 4);
      bf16x8 a[8], bh[4], bl[4];
#pragma unroll
      for (int i = 0; i < 8; ++i) {
        int r = wm * 128 + i * 16 + (lane & 15);
        a[i] = *(const bf16x8*)(ldsA + r * 64 + ((cch ^ (r & 7)) * 8));
      }
#pragma unroll
      for (int i = 0; i < 4; ++i) {
        int n = wn * 64 + i * 16 + (lane & 15);
        bh[i] = *(const bf16x8*)(ldsBh + n * 64 + ((cch ^ (n & 7)) * 8));
        bl[i] = *(const bf16x8*)(ldsBl + n * 64 + ((cch ^ (n & 7)) * 8));
      }
#pragma unroll
      for (int mi = 0; mi < 8; ++mi)
#pragma unroll
        for (int ni = 0; ni < 4; ++ni) {
          acc[mi][ni] = __builtin_amdgcn_mfma_f32_16x16x32_bf16(a[mi], bh[ni], acc[mi][ni], 0, 0, 0);
          acc[mi][ni] = __builtin_amdgcn_mfma_f32_16x16x32_bf16(a[mi], bl[ni], acc[mi][ni], 0, 0, 0);
        }
    }
  }

  // ---- fused epilogue: 4 quarters of 64 rows (= t-pairs, sequential in t).
  float sc[4], sh[4];
#pragma unroll
  for (int ni = 0; ni < 4; ++ni) {
    int oc = wn * 64 + ni * 16 + (lane & 15);
    sc[ni] = bn2_g[oc] * rsqrtf(bn2_v[oc] + 1e-5f);
    sh[ni] = (conv2_b[oc] - bn2_m[oc]) * sc[ni] + bn2_b[oc];
  }
  float* ybuf = (float*)lds;                        // 64 rows x stride 132 floats
  const int S = 132;
  float v[32];
#pragma unroll
  for (int q = 0; q < 32; ++q) v[q] = 0.f;
  unsigned short* p2u = (unsigned short*)p2;
  __syncthreads();
#pragma unroll
  for (int q = 0; q < 4; ++q) {                     // FULLY UNROLLED (acc idx const)
    if (wm == (q >> 1)) {
      const int mib = (q & 1) * 4;
#pragma unroll
      for (int ml = 0; ml < 4; ++ml)
#pragma unroll
        for (int ni = 0; ni < 4; ++ni)
#pragma unroll
          for (int r = 0; r < 4; ++r) {
            int lam = ml * 16 + ((lane >> 4) << 2) + r;
            int col = wn * 64 + ni * 16 + (lane & 15);
            ybuf[lam * S + col] = acc[mib + ml][ni][r] * sc[ni] + sh[ni];
          }
    }
    __syncthreads();
    if (tid < 128) {
      const int oc = tid;
#pragma unroll
      for (int tt = 0; tt < 2; ++tt) {
        int t = 2 * q + tt;
#pragma unroll
        for (int pooly = 0; pooly < 2; ++pooly) {
          unsigned short ov[4];
#pragma unroll
          for (int poolx = 0; poolx < 4; ++poolx) {
            bool any = false;
#pragma unroll
            for (int ry = 0; ry < 2; ++ry)
#pragma unroll
              for (int rx = 0; rx < 2; ++rx) {
                int iy = 2 * pooly + ry, ix = 2 * poolx + rx;
                float xx = ybuf[(tt * 32 + iy * 8 + ix) * S + oc];
                int qi = iy * 8 + ix;
                v[qi] += xx;
                bool ss = v[qi] >= 1.f;
                any |= ss;
                if (ss) v[qi] = 0.f;
              }
            ov[poolx] = any ? (unsigned short)0x3F80 : (unsigned short)0;
          }
          ushort4 o4; o4.x = ov[0]; o4.y = ov[1]; o4.z = ov[2]; o4.w = ov[3];
          *(ushort4*)(p2u + ((size_t)(t * 32 + b) * 128 + oc) * 144 + (2 * gy + pooly) * 12 + 4 * gx) = o4;
        }
      }
    }
    __syncthreads();
  }
}

// fc1: M=256, N=1152, K=18432 split 32 ways.  [R13 state: N-tiles of 64,
// grid 18x32 = 576 blocks, LDS 48KB, acc[4][2], 1-deep B prefetch]
__global__ __launch_bounds__(512) void fc1_gemm(const short* __restrict__ p2,
                                                const float* __restrict__ fc1_w,
                                                float* __restrict__ part) {
  __shared__ __align__(16) short lds[24576];        // A:16384  Bh:4096  Bl:4096 (48 KB)
  short* ldsA = lds;
  short* ldsBh = lds + 16384;
  short* ldsBl = lds + 20480;

  const int tid = threadIdx.x;
  const int lane = tid & 63;
  const int w = tid >> 6;                           // 0..7
  const int wm = w & 3, wn = w >> 2;                // wm: 64-row quarter; wn: 32-col half
  const int nt2 = blockIdx.x;                       // 0..17 N-tile of 64 cols
  const int n0 = nt2 * 64;
  const int kb = blockIdx.y * 576;

  const int g = (lane & 7) ^ (lane >> 3);
  int aofs[4];
#pragma unroll
  for (int j = 0; j < 4; ++j) {
    int r = w * 32 + j * 8 + (lane >> 3);
    aofs[j] = r * 18432 + g * 8;
  }
  const int bn = tid >> 3;                          // 0..63 B row
  const int c0 = tid & 7;                           // chunk of 8 floats
  const float* wrow = fc1_w + (size_t)(n0 + bn) * 18432 + c0 * 8;
  const int bpos = (c0 ^ (bn & 7)) * 8;

  f32x4 acc[4][2];
#pragma unroll
  for (int mi = 0; mi < 4; ++mi)
#pragma unroll
    for (int ni = 0; ni < 2; ++ni) acc[mi][ni] = (f32x4){0.f, 0.f, 0.f, 0.f};

  // prologue: B regs for substage 0
  float4 q0, q1;
  {
    const float4* wp = (const float4*)(wrow + kb);
    q0 = wp[0]; q1 = wp[1];
  }

#pragma unroll 1
  for (int s = 0; s < 9; ++s) {
    const int koff = kb + s * 64;
    __syncthreads();
#pragma unroll
    for (int j = 0; j < 4; ++j) {
      lds_load16(p2 + aofs[j] + koff, ldsA + (w * 32 + j * 8) * 64 + lane * 8);
    }
    {
      unsigned h0, h1, h2, h3, l0, l1, l2, l3;
      split_pair(q0.x, q0.y, h0, l0);
      split_pair(q0.z, q0.w, h1, l1);
      split_pair(q1.x, q1.y, h2, l2);
      split_pair(q1.z, q1.w, h3, l3);
      uint4 H; H.x = h0; H.y = h1; H.z = h2; H.w = h3;
      uint4 L; L.x = l0; L.y = l1; L.z = l2; L.w = l3;
      *(uint4*)(ldsBh + bn * 64 + bpos) = H;
      *(uint4*)(ldsBl + bn * 64 + bpos) = L;
    }
    if (s < 8) {                                    // prefetch next B (consumed next iter)
      const float4* wp = (const float4*)(wrow + koff + 64);
      q0 = wp[0]; q1 = wp[1];
    }
    __builtin_amdgcn_sched_barrier(0);              // keep prefetch above the barrier
    __syncthreads();
#pragma unroll
    for (int ks = 0; ks < 2; ++ks) {
      bf16x8 a[4], bh[2], bl[2];
      const int cch = ks * 4 + (lane >> 4);
#pragma unroll
      for (int i = 0; i < 4; ++i) {
        int r = wm * 64 + i * 16 + (lane & 15);
        a[i] = *(const bf16x8*)(ldsA + r * 64 + ((cch ^ (r & 7)) * 8));
      }
#pragma unroll
      for (int i = 0; i < 2; ++i) {
        int n = wn * 32 + i * 16 + (lane & 15);
        bh[i] = *(const bf16x8*)(ldsBh + n * 64 + ((cch ^ (n & 7)) * 8));
        bl[i] = *(const bf16x8*)(ldsBl + n * 64 + ((cch ^ (n & 7)) * 8));
      }
#pragma unroll
      for (int mi = 0; mi < 4; ++mi)
#pragma unroll
        for (int ni = 0; ni < 2; ++ni) {
          acc[mi][ni] = __builtin_amdgcn_mfma_f32_16x16x32_bf16(a[mi], bh[ni], acc[mi][ni], 0, 0, 0);
          acc[mi][ni] = __builtin_amdgcn_mfma_f32_16x16x32_bf16(a[mi], bl[ni], acc[mi][ni], 0, 0, 0);
        }
    }
  }
  const int nt = nt2 >> 1;                          // 128-col tile for part layout
  const int jbase = (nt2 & 1) * 64;
  const size_t pbase = (size_t)(blockIdx.y * 9 + nt) * 32768;
#pragma unroll
  for (int ni = 0; ni < 2; ++ni) {
    int j = jbase + wn * 32 + ni * 16 + (lane & 15);
#pragma unroll
    for (int mi = 0; mi < 4; ++mi) {
#pragma unroll
      for (int r = 0; r < 4; ++r) {
        int m = wm * 64 + mi * 16 + ((lane >> 4) << 2) + r;
        part[pbase + (size_t)m * 128 + j] = acc[mi][ni][r];
      }
    }
  }
}

// split-K reduce + bias + LIF over T, writing l1 spikes.  [R12/R13 state]
__global__ __launch_bounds__(128) void fc1_reduce_lif(const float* __restrict__ part,
                                                      const float* __restrict__ fc1_b,
                                                      float* __restrict__ l1s) {
  int i = blockIdx.x * 128 + threadIdx.x;           // < 36864 : (b, n)
  int b = i / 1152, n = i - b * 1152;
  int nt = n >> 7, j = n & 127;
  float bias = fc1_b[n];
  float v = 0.f;
#pragma unroll
  for (int t = 0; t < T_STEPS; ++t) {
    int m = t * 32 + b;
    float vals[32];
#pragma unroll
    for (int ks = 0; ks < 32; ++ks)
      vals[ks] = part[(((size_t)ks * 9 + nt) * 256 + m) * 128 + j];
    float s = bias;
#pragma unroll
    for (int ks = 0; ks < 32; ++ks) s += vals[ks];
    v += (s - v) * 0.5f;
    bool sp = v >= 1.f;
    l1s[(size_t)m * 1152 + n] = sp ? 1.f : 0.f;
    if (sp) v = 0.f;
  }
}

// fused tail: fc2 + LIF + fc3 + LIF + mean over T. One block per batch b.
// [R13 monolithic form]
__global__ __launch_bounds__(512) void tail(const float* __restrict__ l1s,
                                            const float* __restrict__ w2t,
                                            const float* __restrict__ b2,
                                            const float* __restrict__ w3,
                                            const float* __restrict__ b3,
                                            float* __restrict__ out) {
  __shared__ float sx[8][1152];                     // l1 spikes for this b (36 KB)
  __shared__ float part2[4][8][128];                // k-chunk partials (16 KB)
  __shared__ float s2[8][128];                      // l2 spikes
  __shared__ float y3[7][8];
  const int b = blockIdx.x;
  const int tid = threadIdx.x;
  for (int i = tid; i < 9216; i += 512) {
    int t = i / 1152, k = i - t * 1152;
    sx[t][k] = l1s[(size_t)(t * 32 + b) * 1152 + k];
  }
  __syncthreads();
  const int o = tid & 127, h = tid >> 7;            // h: 4-way K split
  float p[8];
#pragma unroll
  for (int t = 0; t < 8; ++t) p[t] = 0.f;
#pragma unroll 8
  for (int kk = 0; kk < 288; ++kk) {
    int k = h * 288 + kk;
    float wv = w2t[k * 128 + o];
#pragma unroll
    for (int t = 0; t < 8; ++t) p[t] += sx[t][k] * wv;
  }
#pragma unroll
  for (int t = 0; t < 8; ++t) part2[h][t][o] = p[t];
  __syncthreads();
  if (tid < 128) {
    float v = 0.f;
#pragma unroll
    for (int t = 0; t < 8; ++t) {
      float xx = part2[0][t][o] + part2[1][t][o] + part2[2][t][o] + part2[3][t][o] + b2[o];
      v += (xx - v) * 0.5f;
      bool s = v >= 1.f;
      s2[t][o] = s ? 1.f : 0.f;
      if (s) v = 0.f;
    }
  }
  __syncthreads();
  if (tid < 56) {
    int oo = tid >> 3, t = tid & 7;
    float d = 0.f;
    for (int k = 0; k < 128; ++k) d += s2[t][k] * w3[oo * 128 + k];
    y3[oo][t] = d + b3[oo];
  }
  __syncthreads();
  if (tid < 7) {
    float v = 0.f, a = 0.f;
#pragma unroll
    for (int t = 0; t < 8; ++t) {
      float xx = y3[tid][t];
      v += (xx - v) * 0.5f;
      bool s = v >= 1.f;
      a += s ? 1.f : 0.f;
      if (s) v = 0.f;
    }
    out[b * 7 + tid] = a * 0.125f;
  }
}

// ---------------------------------------------------------------------------
extern "C" void kernel_launch(void* const* d_in, const int* in_sizes, int n_in,
                              void* d_out, int out_size, void* d_ws, size_t ws_size,
                              hipStream_t stream) {
  const float* x       = (const float*)d_in[0];
  const float* conv1_w = (const float*)d_in[1];
  const float* conv1_b = (const float*)d_in[2];
  const float* bn1_g   = (const float*)d_in[3];
  const float* bn1_b   = (const float*)d_in[4];
  const float* bn1_m   = (const float*)d_in[5];
  const float* bn1_v   = (const float*)d_in[6];
  const float* conv2_w = (const float*)d_in[7];
  const float* conv2_b = (const float*)d_in[8];
  const float* bn2_g   = (const float*)d_in[9];
  const float* bn2_b   = (const float*)d_in[10];
  const float* bn2_m   = (const float*)d_in[11];
  const float* bn2_v   = (const float*)d_in[12];
  const float* fc1_w   = (const float*)d_in[13];
  const float* fc1_b   = (const float*)d_in[14];
  const float* fc2_w   = (const float*)d_in[15];
  const float* fc2_b   = (const float*)d_in[16];
  const float* fc3_w   = (const float*)d_in[17];
  const float* fc3_b   = (const float*)d_in[18];

  char* ws = (char*)d_ws;
  short* p1pad = (short*)(ws + OFF_P1);
  float* part  = (float*)(ws + OFF_PART);
  short* wt_hi = (short*)(ws + OFF_WT);
  short* wt_lo = wt_hi + 147456;
  short* p2    = (short*)(ws + OFF_P2);
  float* w2t   = (float*)(ws + OFF_W2T);
  float* l1s   = (float*)(ws + OFF_L1S);
  float* out   = (float*)d_out;

  prep_conv1<<<11968, 256, 0, stream>>>(conv2_w, fc2_w, wt_hi, wt_lo, w2t, (uint4*)p1pad,
                                        x, conv1_w, conv1_b, bn1_g, bn1_b, bn1_m, bn1_v, p1pad);
  conv2_gemm<<<dim3(32, 18), 256, 0, stream>>>(p1pad, wt_hi, wt_lo, conv2_b, bn2_g, bn2_b, bn2_m, bn2_v, p2);
  fc1_gemm<<<dim3(18, 32), 512, 0, stream>>>(p2, fc1_w, part);
  fc1_reduce_lif<<<288, 128, 0, stream>>>(part, fc1_b, l1s);
  tail<<<32, 512, 0, stream>>>(l1s, w2t, fc2_b, fc3_w, fc3_b, out);
}

// Round 14
// 325.001 us; speedup vs baseline: 1.0247x; 1.0117x over previous
//
#include <hip/hip_runtime.h>
#include <hip/hip_bf16.h>

// ---------------------------------------------------------------------------
// SJCSNN: conv1+bn1 -> IF -> pool -> conv2+bn2 -> IF -> pool -> fc1 -> LIF ->
//         fc2 -> LIF -> fc3 -> LIF -> mean over T.  T=8, B=32.
// Spikes are binary => exact in bf16 => MFMA with hi/lo-split fp32 weights
// gives fp32-identical threshold decisions (absmax == 0.0 across rounds).
// conv2 (FROZEN, ~101us): R5 1-phase gload_lds + R11 grid swap (b fastest).
// R12 (kept): fc1_reduce 32-wide load ILP; prep+conv1 merged; tail unroll 8.
// R13 (kept, best 328.1): fc1_gemm N-retile 64 -> 576 blocks (full machine).
// R14-R17 (REVERTED): tail fusion/split, 2-deep prefetch, conv1 grouping --
//   all null or worse.  R18 (kept, null): conv1 uint4 spike stores.
// R19: fc1_gemm grid swap (18,32)->(32,18): kb-split fastest => flat-id%8 ==
//   ksplit%8, so the 18 blocks sharing a p2 K-slice (295KB, read 18x) land
//   on ONE XCD -> slice L2-resident instead of 8x-duplicated/L3-served.
//   A-drain is on fc1's barrier-serialized critical path => latency cut.
//   Pure index relabel (same per-block work, same acc order) => bit-exact.
// ---------------------------------------------------------------------------

typedef float  f32x4  __attribute__((ext_vector_type(4)));
typedef __bf16 bf16x8 __attribute__((ext_vector_type(8)));

#define T_STEPS 8

// ---- workspace layout (bytes) ----
static const size_t OFF_P1    = 0;                  // p1pad 44,302,336 (dead after conv2)
static const size_t OFF_PART  = 0;                  // fc1 partials 37,748,736 (reuse)
static const size_t OFF_WT    = 44302336;           // 1,179,648 (hi+lo conv2 weights)
static const size_t OFF_P2    = 45481984;           // 9,437,184
static const size_t OFF_W2T   = 54919168;           //   589,824
static const size_t OFF_L1S   = 55508992;           // 1,179,648  (end 56,688,640)

__device__ __forceinline__ unsigned short bf16_rne(float f) {
  unsigned u = __builtin_bit_cast(unsigned, f);
  u += 0x7FFFu + ((u >> 16) & 1u);
  return (unsigned short)(u >> 16);
}
__device__ __forceinline__ float bf16_to_f(unsigned short h) {
  unsigned u = ((unsigned)h) << 16;
  return __builtin_bit_cast(float, u);
}

// packed split: two fp32 -> packed hi-bf16 pair + packed lo-bf16 pair.
__device__ __forceinline__ void split_pair(float f0, float f1, unsigned& hi, unsigned& lo) {
  __hip_bfloat162 h2 = __float22bfloat162_rn(make_float2(f0, f1));
  unsigned uh; __builtin_memcpy(&uh, &h2, 4);
  float g0 = __builtin_bit_cast(float, uh << 16);
  float g1 = __builtin_bit_cast(float, uh & 0xFFFF0000u);
  __hip_bfloat162 l2 = __float22bfloat162_rn(make_float2(f0 - g0, f1 - g1));
  unsigned ul; __builtin_memcpy(&ul, &l2, 4);
  hi = uh;
  lo = ul;
}

__device__ __forceinline__ void lds_load16(const void* g, void* l) {
  auto* gp = reinterpret_cast<const __attribute__((address_space(1))) unsigned int*>(
      reinterpret_cast<uintptr_t>(g));
  auto* lp = reinterpret_cast<__attribute__((address_space(3))) unsigned int*>(
      reinterpret_cast<uintptr_t>(l));
  __builtin_amdgcn_global_load_lds(gp, lp, 16, 0, 0);
}

// ---------------------------------------------------------------------------
// merged prep + conv1.  Blocks [0,2752): prep (conv2_w hi/lo split, fc2_w
// transpose, p1pad border zero).  Blocks [2752,11968): conv1+bn1 -> IF(T) ->
// pool, 2 spatial positions per 256-thread block; spike stores staged in LDS
// and written as one uint4 per thread (coalesced 256B rows).
__global__ __launch_bounds__(256) void prep_conv1(
    const float* __restrict__ conv2_w, const float* __restrict__ fc2_w,
    short* __restrict__ wt_hi, short* __restrict__ wt_lo, float* __restrict__ w2t,
    uint4* __restrict__ p1pad4,
    const float* __restrict__ x, const float* __restrict__ w1, const float* __restrict__ b1,
    const float* __restrict__ g1, const float* __restrict__ be1, const float* __restrict__ m1,
    const float* __restrict__ vv1, short* __restrict__ p1) {
  __shared__ float patch[2][16];
  __shared__ __align__(16) unsigned short spike[2][8][128];   // 4 KB
  const int bx = blockIdx.x;
  if (bx < 2752) {
    // ---- prep ----
    int i = bx * 256 + threadIdx.x;                  // < 704512
    if (i < 147456) {
      int tap = i >> 14;
      int oc  = (i >> 7) & 127;
      int ic  = i & 127;
      float wv = conv2_w[oc * 1152 + ic * 9 + tap];
      unsigned short h = bf16_rne(wv);
      wt_hi[i] = (short)h;
      wt_lo[i] = (short)bf16_rne(wv - bf16_to_f(h));
    } else if (i < 294912) {
      int j = i - 147456;
      int o = j & 127, k = j >> 7;
      w2t[j] = fc2_w[o * 1152 + k];
    } else {
      int k = i - 294912;                            // 256 tb x 100 border pos x 16 uint4
      int tb = k / 1600;
      int rem = k - tb * 1600;
      int pos = rem >> 4, c8 = rem & 15;
      int y, xx;
      if (pos < 26)      { y = 0;  xx = pos; }
      else if (pos < 52) { y = 25; xx = pos - 26; }
      else { int jj = pos - 52; y = 1 + (jj >> 1); xx = (jj & 1) * 25; }
      p1pad4[(tb * 676 + y * 26 + xx) * 16 + c8] = make_uint4(0u, 0u, 0u, 0u);
    }
    return;
  }
  // ---- conv1: bid in [0,9216): b = bid/288, sp-pair = bid%288 ----
  const int bid  = bx - 2752;
  const int b    = bid / 288;
  const int spp  = bid - b * 288;
  const int half = threadIdx.x >> 7;                 // 0/1: which sp of the pair
  const int sp   = spp * 2 + half;                   // 0..575
  const int c    = threadIdx.x & 127;
  const int oy = sp / 24, ox = sp % 24;
  if (c < 16) {
    int py = c >> 2, px = c & 3;
    int iy = 2 * oy - 1 + py, ix = 2 * ox - 1 + px;
    float v = 0.f;
    if (iy >= 0 && iy < 48 && ix >= 0 && ix < 48) v = x[b * 2304 + iy * 48 + ix];
    patch[half][c] = v;
  }
  __syncthreads();
  float w[9];
#pragma unroll
  for (int i = 0; i < 9; ++i) w[i] = w1[c * 9 + i];
  float scale = g1[c] * rsqrtf(vv1[c] + 1e-5f);
  float shift = (b1[c] - m1[c]) * scale + be1[c];
  float h[4];
#pragma unroll
  for (int p = 0; p < 4; ++p) {
    int py = p >> 1, px = p & 1;
    float s = 0.f;
#pragma unroll
    for (int dy = 0; dy < 3; ++dy)
#pragma unroll
      for (int dx = 0; dx < 3; ++dx) s += patch[half][(py + dy) * 4 + (px + dx)] * w[dy * 3 + dx];
    h[p] = s * scale + shift;
  }
  float va = 0.f, vb = 0.f, vc = 0.f, vd = 0.f;
#pragma unroll
  for (int t = 0; t < T_STEPS; ++t) {
    va += h[0]; vb += h[1]; vc += h[2]; vd += h[3];
    bool s0 = va >= 1.f, s1 = vb >= 1.f, s2 = vc >= 1.f, s3 = vd >= 1.f;
    spike[half][t][c] = (s0 | s1 | s2 | s3) ? (unsigned short)0x3F80 : (unsigned short)0;
    if (s0) va = 0.f; if (s1) vb = 0.f; if (s2) vc = 0.f; if (s3) vd = 0.f;
  }
  __syncthreads();
  // widened store: tid -> (half, t, 16B chunk); one uint4 per thread.
  {
    const int h2 = threadIdx.x >> 7;
    const int t  = (threadIdx.x >> 4) & 7;
    const int ch = threadIdx.x & 15;
    const int sp2 = spp * 2 + h2;
    const int oy2 = sp2 / 24, ox2 = sp2 % 24;
    size_t rowbase = ((size_t)b * 676 + (size_t)(1 + oy2) * 26 + (1 + ox2)) * 128 + ch * 8;
    uint4 v4 = *(const uint4*)&spike[h2][t][ch * 8];
    *(uint4*)((unsigned short*)p1 + rowbase + (size_t)t * (32 * 676 * 128)) = v4;
  }
}

// conv2 implicit-im2col MFMA GEMM, 256x128 block tile (4 waves x 128x64),
// fused bn2 + IF(T) + 2x2 maxpool epilogue. [FROZEN: R5 structure + R11 swap]
__global__ __launch_bounds__(256, 2) void conv2_gemm(
    const short* __restrict__ p1pad, const short* __restrict__ wt_hi, const short* __restrict__ wt_lo,
    const float* __restrict__ conv2_b, const float* __restrict__ bn2_g, const float* __restrict__ bn2_b,
    const float* __restrict__ bn2_m, const float* __restrict__ bn2_v, short* __restrict__ p2) {
  __shared__ __align__(16) short lds[32768];        // A:16384  Bh:8192  Bl:8192 shorts (64 KB)
  short* ldsA  = lds;
  short* ldsBh = lds + 16384;
  short* ldsBl = lds + 24576;

  const int tid = threadIdx.x;
  const int lane = tid & 63;
  const int w = tid >> 6;                           // 0..3
  const int wm = w & 1, wn = w >> 1;
  const int b  = blockIdx.x;                        // b fastest -> XCD = b%8
  const int sp = blockIdx.y;                        // 0..17 spatial tile
  const int gy = sp / 3;
  const int gx = sp - gy * 3;

  const int g = (lane & 7) ^ (lane >> 3);
  int rowofsA[8], bofs[4];
#pragma unroll
  for (int j = 0; j < 8; ++j) {
    int r = w * 64 + j * 8 + (lane >> 3);
    int t = r >> 5, iy = (r >> 3) & 3, ix = r & 7;
    rowofsA[j] = (((t * 32 + b) * 676) + (4 * gy + iy) * 26 + (8 * gx + ix)) * 128 + g * 8;
  }
#pragma unroll
  for (int j = 0; j < 4; ++j) {
    int n = w * 32 + j * 8 + (lane >> 3);
    bofs[j] = n * 128 + g * 8;
  }

  f32x4 acc[8][4];
#pragma unroll
  for (int mi = 0; mi < 8; ++mi)
#pragma unroll
    for (int ni = 0; ni < 4; ++ni) acc[mi][ni] = (f32x4){0.f, 0.f, 0.f, 0.f};

#pragma unroll 1
  for (int s = 0; s < 18; ++s) {
    const int tap = s >> 1;
    const int kk = (s & 1) << 6;
    const int tapoff = ((tap / 3) * 26 + (tap % 3)) * 128;
    __syncthreads();
#pragma unroll
    for (int j = 0; j < 8; ++j) {
      lds_load16(p1pad + rowofsA[j] + tapoff + kk, ldsA + (w * 64 + j * 8) * 64 + lane * 8);
    }
    const int wtoff = tap * 16384 + kk;
#pragma unroll
    for (int j = 0; j < 4; ++j) {
      lds_load16(wt_hi + wtoff + bofs[j], ldsBh + (w * 32 + j * 8) * 64 + lane * 8);
      lds_load16(wt_lo + wtoff + bofs[j], ldsBl + (w * 32 + j * 8) * 64 + lane * 8);
    }
    __syncthreads();
#pragma unroll
    for (int ks = 0; ks < 2; ++ks) {
      const int cch = ks * 4 + (lane >> 4);
      bf16x8 a[8], bh[4], bl[4];
#pragma unroll
      for (int i = 0; i < 8; ++i) {
        int r = wm * 128 + i * 16 + (lane & 15);
        a[i] = *(const bf16x8*)(ldsA + r * 64 + ((cch ^ (r & 7)) * 8));
      }
#pragma unroll
      for (int i = 0; i < 4; ++i) {
        int n = wn * 64 + i * 16 + (lane & 15);
        bh[i] = *(const bf16x8*)(ldsBh + n * 64 + ((cch ^ (n & 7)) * 8));
        bl[i] = *(const bf16x8*)(ldsBl + n * 64 + ((cch ^ (n & 7)) * 8));
      }
#pragma unroll
      for (int mi = 0; mi < 8; ++mi)
#pragma unroll
        for (int ni = 0; ni < 4; ++ni) {
          acc[mi][ni] = __builtin_amdgcn_mfma_f32_16x16x32_bf16(a[mi], bh[ni], acc[mi][ni], 0, 0, 0);
          acc[mi][ni] = __builtin_amdgcn_mfma_f32_16x16x32_bf16(a[mi], bl[ni], acc[mi][ni], 0, 0, 0);
        }
    }
  }

  // ---- fused epilogue: 4 quarters of 64 rows (= t-pairs, sequential in t).
  float sc[4], sh[4];
#pragma unroll
  for (int ni = 0; ni < 4; ++ni) {
    int oc = wn * 64 + ni * 16 + (lane & 15);
    sc[ni] = bn2_g[oc] * rsqrtf(bn2_v[oc] + 1e-5f);
    sh[ni] = (conv2_b[oc] - bn2_m[oc]) * sc[ni] + bn2_b[oc];
  }
  float* ybuf = (float*)lds;                        // 64 rows x stride 132 floats
  const int S = 132;
  float v[32];
#pragma unroll
  for (int q = 0; q < 32; ++q) v[q] = 0.f;
  unsigned short* p2u = (unsigned short*)p2;
  __syncthreads();
#pragma unroll
  for (int q = 0; q < 4; ++q) {                     // FULLY UNROLLED (acc idx const)
    if (wm == (q >> 1)) {
      const int mib = (q & 1) * 4;
#pragma unroll
      for (int ml = 0; ml < 4; ++ml)
#pragma unroll
        for (int ni = 0; ni < 4; ++ni)
#pragma unroll
          for (int r = 0; r < 4; ++r) {
            int lam = ml * 16 + ((lane >> 4) << 2) + r;
            int col = wn * 64 + ni * 16 + (lane & 15);
            ybuf[lam * S + col] = acc[mib + ml][ni][r] * sc[ni] + sh[ni];
          }
    }
    __syncthreads();
    if (tid < 128) {
      const int oc = tid;
#pragma unroll
      for (int tt = 0; tt < 2; ++tt) {
        int t = 2 * q + tt;
#pragma unroll
        for (int pooly = 0; pooly < 2; ++pooly) {
          unsigned short ov[4];
#pragma unroll
          for (int poolx = 0; poolx < 4; ++poolx) {
            bool any = false;
#pragma unroll
            for (int ry = 0; ry < 2; ++ry)
#pragma unroll
              for (int rx = 0; rx < 2; ++rx) {
                int iy = 2 * pooly + ry, ix = 2 * poolx + rx;
                float xx = ybuf[(tt * 32 + iy * 8 + ix) * S + oc];
                int qi = iy * 8 + ix;
                v[qi] += xx;
                bool ss = v[qi] >= 1.f;
                any |= ss;
                if (ss) v[qi] = 0.f;
              }
            ov[poolx] = any ? (unsigned short)0x3F80 : (unsigned short)0;
          }
          ushort4 o4; o4.x = ov[0]; o4.y = ov[1]; o4.z = ov[2]; o4.w = ov[3];
          *(ushort4*)(p2u + ((size_t)(t * 32 + b) * 128 + oc) * 144 + (2 * gy + pooly) * 12 + 4 * gx) = o4;
        }
      }
    }
    __syncthreads();
  }
}

// fc1: M=256, N=1152, K=18432 split 32 ways.  [R13 tiling: N-tiles of 64,
// 576 blocks, LDS 48KB, acc[4][2], 1-deep B prefetch]
// R19: grid (32,18) with K-split fastest -> same-kb blocks (18 readers of
// one 295KB p2 K-slice) share an XCD's L2.  Same per-block work => exact.
__global__ __launch_bounds__(512) void fc1_gemm(const short* __restrict__ p2,
                                                const float* __restrict__ fc1_w,
                                                float* __restrict__ part) {
  __shared__ __align__(16) short lds[24576];        // A:16384  Bh:4096  Bl:4096 (48 KB)
  short* ldsA = lds;
  short* ldsBh = lds + 16384;
  short* ldsBl = lds + 20480;

  const int tid = threadIdx.x;
  const int lane = tid & 63;
  const int w = tid >> 6;                           // 0..7
  const int wm = w & 3, wn = w >> 2;                // wm: 64-row quarter; wn: 32-col half
  const int ksp = blockIdx.x;                       // 0..31 K-split (fastest -> XCD = ksp%8)
  const int nt2 = blockIdx.y;                       // 0..17 N-tile of 64 cols
  const int n0 = nt2 * 64;
  const int kb = ksp * 576;

  const int g = (lane & 7) ^ (lane >> 3);
  int aofs[4];
#pragma unroll
  for (int j = 0; j < 4; ++j) {
    int r = w * 32 + j * 8 + (lane >> 3);
    aofs[j] = r * 18432 + g * 8;
  }
  const int bn = tid >> 3;                          // 0..63 B row
  const int c0 = tid & 7;                           // chunk of 8 floats
  const float* wrow = fc1_w + (size_t)(n0 + bn) * 18432 + c0 * 8;
  const int bpos = (c0 ^ (bn & 7)) * 8;

  f32x4 acc[4][2];
#pragma unroll
  for (int mi = 0; mi < 4; ++mi)
#pragma unroll
    for (int ni = 0; ni < 2; ++ni) acc[mi][ni] = (f32x4){0.f, 0.f, 0.f, 0.f};

  // prologue: B regs for substage 0
  float4 q0, q1;
  {
    const float4* wp = (const float4*)(wrow + kb);
    q0 = wp[0]; q1 = wp[1];
  }

#pragma unroll 1
  for (int s = 0; s < 9; ++s) {
    const int koff = kb + s * 64;
    __syncthreads();
#pragma unroll
    for (int j = 0; j < 4; ++j) {
      lds_load16(p2 + aofs[j] + koff, ldsA + (w * 32 + j * 8) * 64 + lane * 8);
    }
    {
      unsigned h0, h1, h2, h3, l0, l1, l2, l3;
      split_pair(q0.x, q0.y, h0, l0);
      split_pair(q0.z, q0.w, h1, l1);
      split_pair(q1.x, q1.y, h2, l2);
      split_pair(q1.z, q1.w, h3, l3);
      uint4 H; H.x = h0; H.y = h1; H.z = h2; H.w = h3;
      uint4 L; L.x = l0; L.y = l1; L.z = l2; L.w = l3;
      *(uint4*)(ldsBh + bn * 64 + bpos) = H;
      *(uint4*)(ldsBl + bn * 64 + bpos) = L;
    }
    if (s < 8) {                                    // prefetch next B (consumed next iter)
      const float4* wp = (const float4*)(wrow + koff + 64);
      q0 = wp[0]; q1 = wp[1];
    }
    __builtin_amdgcn_sched_barrier(0);              // keep prefetch above the barrier
    __syncthreads();
#pragma unroll
    for (int ks = 0; ks < 2; ++ks) {
      bf16x8 a[4], bh[2], bl[2];
      const int cch = ks * 4 + (lane >> 4);
#pragma unroll
      for (int i = 0; i < 4; ++i) {
        int r = wm * 64 + i * 16 + (lane & 15);
        a[i] = *(const bf16x8*)(ldsA + r * 64 + ((cch ^ (r & 7)) * 8));
      }
#pragma unroll
      for (int i = 0; i < 2; ++i) {
        int n = wn * 32 + i * 16 + (lane & 15);
        bh[i] = *(const bf16x8*)(ldsBh + n * 64 + ((cch ^ (n & 7)) * 8));
        bl[i] = *(const bf16x8*)(ldsBl + n * 64 + ((cch ^ (n & 7)) * 8));
      }
#pragma unroll
      for (int mi = 0; mi < 4; ++mi)
#pragma unroll
        for (int ni = 0; ni < 2; ++ni) {
          acc[mi][ni] = __builtin_amdgcn_mfma_f32_16x16x32_bf16(a[mi], bh[ni], acc[mi][ni], 0, 0, 0);
          acc[mi][ni] = __builtin_amdgcn_mfma_f32_16x16x32_bf16(a[mi], bl[ni], acc[mi][ni], 0, 0, 0);
        }
    }
  }
  const int nt = nt2 >> 1;                          // 128-col tile for part layout
  const int jbase = (nt2 & 1) * 64;
  const size_t pbase = (size_t)(ksp * 9 + nt) * 32768;
#pragma unroll
  for (int ni = 0; ni < 2; ++ni) {
    int j = jbase + wn * 32 + ni * 16 + (lane & 15);
#pragma unroll
    for (int mi = 0; mi < 4; ++mi) {
#pragma unroll
      for (int r = 0; r < 4; ++r) {
        int m = wm * 64 + mi * 16 + ((lane >> 4) << 2) + r;
        part[pbase + (size_t)m * 128 + j] = acc[mi][ni][r];
      }
    }
  }
}

// split-K reduce + bias + LIF over T, writing l1 spikes.  [R12/R13 state]
__global__ __launch_bounds__(128) void fc1_reduce_lif(const float* __restrict__ part,
                                                      const float* __restrict__ fc1_b,
                                                      float* __restrict__ l1s) {
  int i = blockIdx.x * 128 + threadIdx.x;           // < 36864 : (b, n)
  int b = i / 1152, n = i - b * 1152;
  int nt = n >> 7, j = n & 127;
  float bias = fc1_b[n];
  float v = 0.f;
#pragma unroll
  for (int t = 0; t < T_STEPS; ++t) {
    int m = t * 32 + b;
    float vals[32];
#pragma unroll
    for (int ks = 0; ks < 32; ++ks)
      vals[ks] = part[(((size_t)ks * 9 + nt) * 256 + m) * 128 + j];
    float s = bias;
#pragma unroll
    for (int ks = 0; ks < 32; ++ks) s += vals[ks];
    v += (s - v) * 0.5f;
    bool sp = v >= 1.f;
    l1s[(size_t)m * 1152 + n] = sp ? 1.f : 0.f;
    if (sp) v = 0.f;
  }
}

// fused tail: fc2 + LIF + fc3 + LIF + mean over T. One block per batch b.
// [R13 monolithic form]
__global__ __launch_bounds__(512) void tail(const float* __restrict__ l1s,
                                            const float* __restrict__ w2t,
                                            const float* __restrict__ b2,
                                            const float* __restrict__ w3,
                                            const float* __restrict__ b3,
                                            float* __restrict__ out) {
  __shared__ float sx[8][1152];                     // l1 spikes for this b (36 KB)
  __shared__ float part2[4][8][128];                // k-chunk partials (16 KB)
  __shared__ float s2[8][128];                      // l2 spikes
  __shared__ float y3[7][8];
  const int b = blockIdx.x;
  const int tid = threadIdx.x;
  for (int i = tid; i < 9216; i += 512) {
    int t = i / 1152, k = i - t * 1152;
    sx[t][k] = l1s[(size_t)(t * 32 + b) * 1152 + k];
  }
  __syncthreads();
  const int o = tid & 127, h = tid >> 7;            // h: 4-way K split
  float p[8];
#pragma unroll
  for (int t = 0; t < 8; ++t) p[t] = 0.f;
#pragma unroll 8
  for (int kk = 0; kk < 288; ++kk) {
    int k = h * 288 + kk;
    float wv = w2t[k * 128 + o];
#pragma unroll
    for (int t = 0; t < 8; ++t) p[t] += sx[t][k] * wv;
  }
#pragma unroll
  for (int t = 0; t < 8; ++t) part2[h][t][o] = p[t];
  __syncthreads();
  if (tid < 128) {
    float v = 0.f;
#pragma unroll
    for (int t = 0; t < 8; ++t) {
      float xx = part2[0][t][o] + part2[1][t][o] + part2[2][t][o] + part2[3][t][o] + b2[o];
      v += (xx - v) * 0.5f;
      bool s = v >= 1.f;
      s2[t][o] = s ? 1.f : 0.f;
      if (s) v = 0.f;
    }
  }
  __syncthreads();
  if (tid < 56) {
    int oo = tid >> 3, t = tid & 7;
    float d = 0.f;
    for (int k = 0; k < 128; ++k) d += s2[t][k] * w3[oo * 128 + k];
    y3[oo][t] = d + b3[oo];
  }
  __syncthreads();
  if (tid < 7) {
    float v = 0.f, a = 0.f;
#pragma unroll
    for (int t = 0; t < 8; ++t) {
      float xx = y3[tid][t];
      v += (xx - v) * 0.5f;
      bool s = v >= 1.f;
      a += s ? 1.f : 0.f;
      if (s) v = 0.f;
    }
    out[b * 7 + tid] = a * 0.125f;
  }
}

// ---------------------------------------------------------------------------
extern "C" void kernel_launch(void* const* d_in, const int* in_sizes, int n_in,
                              void* d_out, int out_size, void* d_ws, size_t ws_size,
                              hipStream_t stream) {
  const float* x       = (const float*)d_in[0];
  const float* conv1_w = (const float*)d_in[1];
  const float* conv1_b = (const float*)d_in[2];
  const float* bn1_g   = (const float*)d_in[3];
  const float* bn1_b   = (const float*)d_in[4];
  const float* bn1_m   = (const float*)d_in[5];
  const float* bn1_v   = (const float*)d_in[6];
  const float* conv2_w = (const float*)d_in[7];
  const float* conv2_b = (const float*)d_in[8];
  const float* bn2_g   = (const float*)d_in[9];
  const float* bn2_b   = (const float*)d_in[10];
  const float* bn2_m   = (const float*)d_in[11];
  const float* bn2_v   = (const float*)d_in[12];
  const float* fc1_w   = (const float*)d_in[13];
  const float* fc1_b   = (const float*)d_in[14];
  const float* fc2_w   = (const float*)d_in[15];
  const float* fc2_b   = (const float*)d_in[16];
  const float* fc3_w   = (const float*)d_in[17];
  const float* fc3_b   = (const float*)d_in[18];

  char* ws = (char*)d_ws;
  short* p1pad = (short*)(ws + OFF_P1);
  float* part  = (float*)(ws + OFF_PART);
  short* wt_hi = (short*)(ws + OFF_WT);
  short* wt_lo = wt_hi + 147456;
  short* p2    = (short*)(ws + OFF_P2);
  float* w2t   = (float*)(ws + OFF_W2T);
  float* l1s   = (float*)(ws + OFF_L1S);
  float* out   = (float*)d_out;

  prep_conv1<<<11968, 256, 0, stream>>>(conv2_w, fc2_w, wt_hi, wt_lo, w2t, (uint4*)p1pad,
                                        x, conv1_w, conv1_b, bn1_g, bn1_b, bn1_m, bn1_v, p1pad);
  conv2_gemm<<<dim3(32, 18), 256, 0, stream>>>(p1pad, wt_hi, wt_lo, conv2_b, bn2_g, bn2_b, bn2_m, bn2_v, p2);
  fc1_gemm<<<dim3(32, 18), 512, 0, stream>>>(p2, fc1_w, part);
  fc1_reduce_lif<<<288, 128, 0, stream>>>(part, fc1_b, l1s);
  tail<<<32, 512, 0, stream>>>(l1s, w2t, fc2_b, fc3_w, fc3_b, out);
}